// Round 10
// baseline (377.787 us; speedup 1.0000x reference)
//
#include <hip/hip_runtime.h>
#include <cstdint>
#include <cstddef>

#define EPSV 1e-5f
#define NPIX 9216          // 96*96
#define LDA 136            // padded bf16 k-stride for 128-wide K chunks
#define LDK 72             // padded bf16 k-stride for 64-wide K chunks

typedef __bf16 bf16;
typedef _Float16 f16;
typedef __attribute__((ext_vector_type(8))) __bf16 bf16x8;
typedef __attribute__((ext_vector_type(4))) __bf16 bf16x4;
typedef __attribute__((ext_vector_type(2))) _Float16 f16x2;
typedef __attribute__((ext_vector_type(4))) float  f32x4;

__device__ __forceinline__ float silu_f(float v) { return v / (1.f + __expf(-v)); }

// ---------------------------------------------------------------------------
// WTSf (float, 608): b1[128] | b1b[128] | b2[128] | bom[224]
// WTSb (bf16, 249856), all [co][ci]:
//   0       W1b  [128][256]  (x1 1x1, BN-folded)
//   32768   W1bb [128][64]   (x2 1x1, BN-folded)
//   40960   W2b  [9][128][128] (3x3 s2, BN-folded, k-major)
//   188416  Wipb [128][128]
//   204800  Womb [224][128]  (rows 216..223 zero)
//   233472  Wopb [128][128]
// ---------------------------------------------------------------------------
__global__ __launch_bounds__(256) void prep_kernel(
    const float* __restrict__ conv_w, const float* __restrict__ conv_g,
    const float* __restrict__ conv_b, const float* __restrict__ conv_rm, const float* __restrict__ conv_rv,
    const float* __restrict__ conv1_w, const float* __restrict__ conv1_g,
    const float* __restrict__ conv1_b, const float* __restrict__ conv1_rm, const float* __restrict__ conv1_rv,
    const float* __restrict__ conv2_w, const float* __restrict__ conv2_g,
    const float* __restrict__ conv2_bb, const float* __restrict__ conv2_rm, const float* __restrict__ conv2_rv,
    const float* __restrict__ ip_w, const float* __restrict__ op_w,
    const float* __restrict__ off_w, const float* __restrict__ m_w,
    const float* __restrict__ off_b, const float* __restrict__ m_b,
    float* __restrict__ WTSf, bf16* __restrict__ WTSb)
{
  int idx = blockIdx.x * 256 + threadIdx.x;
  if (idx < 608) {
    if (idx < 128) {
      int co = idx;
      float s = conv_g[co] * rsqrtf(conv_rv[co] + EPSV);
      WTSf[idx] = conv_b[co] - conv_rm[co] * s;
    } else if (idx < 256) {
      int co = idx - 128;
      float s = conv1_g[co] * rsqrtf(conv1_rv[co] + EPSV);
      WTSf[idx] = conv1_b[co] - conv1_rm[co] * s;
    } else if (idx < 384) {
      int co = idx - 256;
      float s = conv2_g[co] * rsqrtf(conv2_rv[co] + EPSV);
      WTSf[idx] = conv2_bb[co] - conv2_rm[co] * s;
    } else {
      int col = idx - 384;
      WTSf[idx] = (col < 144) ? off_b[col] : (col < 216 ? m_b[col - 144] : 0.f);
    }
  } else {
    int j = idx - 608;
    if (j < 32768) {
      int co = j >> 8, ci = j & 255;
      float s = conv_g[co] * rsqrtf(conv_rv[co] + EPSV);
      WTSb[j] = (bf16)(conv_w[co * 256 + ci] * s);
    } else if (j < 40960) {
      int r = j - 32768; int co = r >> 6, ci = r & 63;
      float s = conv1_g[co] * rsqrtf(conv1_rv[co] + EPSV);
      WTSb[j] = (bf16)(conv1_w[co * 64 + ci] * s);
    } else if (j < 188416) {
      int r = j - 40960; int kp = r >> 14; int rr = r & 16383;
      int co = rr >> 7, ci = rr & 127;
      float s = conv2_g[co] * rsqrtf(conv2_rv[co] + EPSV);
      WTSb[j] = (bf16)(conv2_w[(co * 128 + ci) * 9 + kp] * s);
    } else if (j < 204800) {
      int r = j - 188416; int co = r >> 7, ci = r & 127;
      WTSb[j] = (bf16)ip_w[co * 128 + ci];
    } else if (j < 233472) {
      int r = j - 204800; int co = r >> 7, ci = r & 127;
      float v = (co < 144) ? off_w[co * 128 + ci] : (co < 216 ? m_w[(co - 144) * 128 + ci] : 0.f);
      WTSb[j] = (bf16)v;
    } else if (j < 249856) {
      int r = j - 233472; int co = r >> 7, ci = r & 127;
      WTSb[j] = (bf16)op_w[co * 128 + ci];
    }
  }
}

// ---------------------------------------------------------------------------
// 1x1 conv body via MFMA: NCHW fp32 (K ch) -> NHWC bf16 (128 ch) + BN + SiLU
// ---------------------------------------------------------------------------
__device__ __forceinline__ void c1x1_body(
    bf16* As, bf16* Bs, const float* __restrict__ x, const bf16* __restrict__ W,
    const float* __restrict__ bias, int K, int HW, int m0, bf16* __restrict__ outb)
{
  int t = threadIdx.x;
  int n = m0 / HW; int hw0 = m0 - n * HW;
  const float* xn = x + (size_t)n * K * HW;
  int wv = t >> 6, lane = t & 63;
  int lrow = lane & 15, q = lane >> 4;
  int n0 = wv * 32;
  f32x4 acc[4][2];
#pragma unroll
  for (int i = 0; i < 4; ++i)
#pragma unroll
    for (int j = 0; j < 2; ++j)
#pragma unroll
      for (int e = 0; e < 4; ++e) acc[i][j][e] = 0.f;

  for (int k0 = 0; k0 < K; k0 += 64) {
    if (k0) __syncthreads();
    for (int i = t; i < 1024; i += 256) {
      int px = i & 63; int ci4 = (i >> 6) << 2;
      bf16x4 p;
#pragma unroll
      for (int j = 0; j < 4; ++j)
        p[j] = (bf16)xn[(size_t)(k0 + ci4 + j) * HW + hw0 + px];
      *(bf16x4*)&As[px * LDK + ci4] = p;
    }
    for (int i = t; i < 1024; i += 256) {
      int co = i >> 3; int k8 = (i & 7) << 3;
      *(bf16x8*)&Bs[co * LDK + k8] = *(const bf16x8*)&W[(size_t)co * K + k0 + k8];
    }
    __syncthreads();
#pragma unroll
    for (int ks = 0; ks < 2; ++ks) {
      int ko = ks * 32 + q * 8;
      bf16x8 bfr0 = *(const bf16x8*)&Bs[(n0 + lrow) * LDK + ko];
      bf16x8 bfr1 = *(const bf16x8*)&Bs[(n0 + 16 + lrow) * LDK + ko];
#pragma unroll
      for (int mi = 0; mi < 4; ++mi) {
        bf16x8 afr = *(const bf16x8*)&As[(mi * 16 + lrow) * LDK + ko];
        acc[mi][0] = __builtin_amdgcn_mfma_f32_16x16x32_bf16(afr, bfr0, acc[mi][0], 0, 0, 0);
        acc[mi][1] = __builtin_amdgcn_mfma_f32_16x16x32_bf16(afr, bfr1, acc[mi][1], 0, 0, 0);
      }
    }
  }
#pragma unroll
  for (int mi = 0; mi < 4; ++mi) {
#pragma unroll
    for (int nj = 0; nj < 2; ++nj) {
      int co = n0 + nj * 16 + lrow;
      float bb = bias[co];
#pragma unroll
      for (int r = 0; r < 4; ++r) {
        int m = m0 + mi * 16 + q * 4 + r;
        outb[(size_t)m * 128 + co] = (bf16)silu_f(acc[mi][nj][r] + bb);
      }
    }
  }
}

// ---------------------------------------------------------------------------
// DUAL 1x1 conv launch: blocks [0,2304) = x2 path (K=64), [2304,2448) = x1
// path (K=256). Independent I/O; merging packs the 144-block x1 conv into
// the x2 conv's shadow instead of a nearly-idle dispatch.
// ---------------------------------------------------------------------------
__global__ __launch_bounds__(256) void c1x1_dual_kernel(
    const float* __restrict__ x1, const bf16* __restrict__ W1b, const float* __restrict__ b1f,
    const float* __restrict__ x2, const bf16* __restrict__ W1bb, const float* __restrict__ b1bf,
    bf16* __restrict__ y1b, bf16* __restrict__ y2b)
{
  __shared__ bf16 As[64 * LDK];
  __shared__ bf16 Bs[128 * LDK];
  int bid = blockIdx.x;
  if (bid < 2304) {
    c1x1_body(As, Bs, x2, W1bb, b1bf, 64, 36864, bid << 6, y2b);
  } else {
    c1x1_body(As, Bs, x1, W1b, b1f, 256, 2304, (bid - 2304) << 6, y1b);
  }
}

// ---------------------------------------------------------------------------
// upsample+ip body (16 px tile, LDS pointers supplied)
// ---------------------------------------------------------------------------
__device__ __forceinline__ void upsample_ip_body(
    bf16* Ds, bf16* Xs, const bf16* __restrict__ y1b, const bf16* __restrict__ Wip,
    const float* __restrict__ ip_b, bf16* __restrict__ feat1b, bf16* __restrict__ xpb,
    int wg)
{
  int t = threadIdx.x;
  int pixel0 = wg * 16;
  {
    int pxl = t >> 4;
    int c8 = (t & 15) << 3;
    int pixel = pixel0 + pxl;
    int n = pixel / NPIX; int hw = pixel - n * NPIX;
    int oh = hw / 96; int ow = hw - oh * 96;
    float sh = oh * 0.5f - 0.25f, sw = ow * 0.5f - 0.25f;
    float hf = floorf(sh), wf = floorf(sw);
    float fy = sh - hf, fx = sw - wf;
    int h0 = (int)hf, w0 = (int)wf;
    int h0c = max(h0, 0), h1c = min(h0 + 1, 47);
    int w0c = max(w0, 0), w1c = min(w0 + 1, 47);
    const bf16* yn = y1b + (size_t)n * 2304 * 128 + c8;
    bf16x8 v00 = *(const bf16x8*)&yn[(h0c * 48 + w0c) * 128];
    bf16x8 v01 = *(const bf16x8*)&yn[(h0c * 48 + w1c) * 128];
    bf16x8 v10 = *(const bf16x8*)&yn[(h1c * 48 + w0c) * 128];
    bf16x8 v11 = *(const bf16x8*)&yn[(h1c * 48 + w1c) * 128];
    bf16x8 o;
#pragma unroll
    for (int e = 0; e < 8; ++e) {
      float v = (1.f - fy) * ((1.f - fx) * (float)v00[e] + fx * (float)v01[e])
              + fy * ((1.f - fx) * (float)v10[e] + fx * (float)v11[e]);
      o[e] = (bf16)v;
    }
    *(bf16x8*)&feat1b[(size_t)pixel * 128 + c8] = o;
    *(bf16x8*)&Ds[pxl * LDA + c8] = o;
  }
  __syncthreads();
  {
    int wv = t >> 6, lane = t & 63;
    int lrow = lane & 15, q = lane >> 4;
    int n0 = wv * 32;
    f32x4 pacc[2];
#pragma unroll
    for (int j = 0; j < 2; ++j)
#pragma unroll
      for (int e = 0; e < 4; ++e) pacc[j][e] = 0.f;
#pragma unroll
    for (int ks = 0; ks < 4; ++ks) {
      int ko = ks * 32 + q * 8;
      bf16x8 afr  = *(const bf16x8*)&Ds[lrow * LDA + ko];
      bf16x8 bfr0 = *(const bf16x8*)&Wip[(size_t)(n0 + lrow) * 128 + ko];
      bf16x8 bfr1 = *(const bf16x8*)&Wip[(size_t)(n0 + 16 + lrow) * 128 + ko];
      pacc[0] = __builtin_amdgcn_mfma_f32_16x16x32_bf16(afr, bfr0, pacc[0], 0, 0, 0);
      pacc[1] = __builtin_amdgcn_mfma_f32_16x16x32_bf16(afr, bfr1, pacc[1], 0, 0, 0);
    }
#pragma unroll
    for (int nj = 0; nj < 2; ++nj) {
      int col = n0 + nj * 16 + lrow;
      float bb = ip_b[col];
#pragma unroll
      for (int r = 0; r < 4; ++r)
        Xs[(q * 4 + r) * LDA + col] = (bf16)(pacc[nj][r] + bb);
    }
  }
  __syncthreads();
  {
    int pxl = t >> 4;
    int c8 = (t & 15) << 3;
    *(bf16x8*)&xpb[(size_t)(pixel0 + pxl) * 128 + c8] = *(const bf16x8*)&Xs[pxl * LDA + c8];
  }
}

// ---------------------------------------------------------------------------
// conv2+ip body (64 px tile, LDS pointers supplied)
// ---------------------------------------------------------------------------
__device__ __forceinline__ void conv2_ip_body(
    bf16* As, bf16* Bs, const bf16* __restrict__ y2b, const bf16* __restrict__ W2b,
    const float* __restrict__ b2, const bf16* __restrict__ Wip,
    const float* __restrict__ ip_b, bf16* __restrict__ feat2b, bf16* __restrict__ xpb,
    int m0)
{
  int t = threadIdx.x;
  int wv = t >> 6, lane = t & 63;
  int lrow = lane & 15, q = lane >> 4;
  int n0 = wv * 32;
  f32x4 acc[4][2];
#pragma unroll
  for (int i = 0; i < 4; ++i)
#pragma unroll
    for (int j = 0; j < 2; ++j)
#pragma unroll
      for (int e = 0; e < 4; ++e) acc[i][j][e] = 0.f;
  bf16x8 zv;
#pragma unroll
  for (int e = 0; e < 8; ++e) zv[e] = (bf16)0.f;

  for (int kp = 0; kp < 9; ++kp) {
    int kh = kp / 3, kw = kp - kh * 3;
    __syncthreads();
    for (int i = t; i < 1024; i += 256) {
      int row = i >> 4; int c8 = (i & 15) << 3;
      int m = m0 + row;
      int nimg = m / NPIX; int hw = m - nimg * NPIX;
      int oh = hw / 96, ow = hw - oh * 96;
      int ih = 2 * oh - 1 + kh, iw = 2 * ow - 1 + kw;
      bf16x8 v = zv;
      if ((unsigned)ih < 192u && (unsigned)iw < 192u)
        v = *(const bf16x8*)&y2b[(((size_t)nimg * 192 + ih) * 192 + iw) * 128 + c8];
      *(bf16x8*)&As[row * LDA + c8] = v;
    }
    const bf16* Wk = W2b + kp * 16384;
    for (int i = t; i < 2048; i += 256) {
      int nn = i >> 4; int k8 = (i & 15) << 3;
      *(bf16x8*)&Bs[nn * LDA + k8] = *(const bf16x8*)&Wk[nn * 128 + k8];
    }
    __syncthreads();
#pragma unroll
    for (int ks = 0; ks < 4; ++ks) {
      bf16x8 bfr0 = *(const bf16x8*)&Bs[(n0 + lrow) * LDA + ks * 32 + q * 8];
      bf16x8 bfr1 = *(const bf16x8*)&Bs[(n0 + 16 + lrow) * LDA + ks * 32 + q * 8];
#pragma unroll
      for (int mi = 0; mi < 4; ++mi) {
        bf16x8 afr = *(const bf16x8*)&As[(mi * 16 + lrow) * LDA + ks * 32 + q * 8];
        acc[mi][0] = __builtin_amdgcn_mfma_f32_16x16x32_bf16(afr, bfr0, acc[mi][0], 0, 0, 0);
        acc[mi][1] = __builtin_amdgcn_mfma_f32_16x16x32_bf16(afr, bfr1, acc[mi][1], 0, 0, 0);
      }
    }
  }
  __syncthreads();                      // all waves done with Bs
  bf16* Fs = Bs;                        // feat tile [64][LDA]
#pragma unroll
  for (int mi = 0; mi < 4; ++mi) {
#pragma unroll
    for (int nj = 0; nj < 2; ++nj) {
      int co = n0 + nj * 16 + lrow;
      float bb = b2[co];
#pragma unroll
      for (int r = 0; r < 4; ++r) {
        int row = mi * 16 + q * 4 + r;
        Fs[row * LDA + co] = (bf16)silu_f(acc[mi][nj][r] + bb);
      }
    }
  }
  __syncthreads();                      // Fs complete
  bf16* Xs = As;                        // As dead
  {
    int mrow0 = wv * 16;
    for (int g = 0; g < 4; ++g) {
      int ng = g * 32;
      f32x4 pacc[2];
#pragma unroll
      for (int j = 0; j < 2; ++j)
#pragma unroll
        for (int e = 0; e < 4; ++e) pacc[j][e] = 0.f;
#pragma unroll
      for (int ks = 0; ks < 4; ++ks) {
        int ko = ks * 32 + q * 8;
        bf16x8 afr  = *(const bf16x8*)&Fs[(mrow0 + lrow) * LDA + ko];
        bf16x8 bfr0 = *(const bf16x8*)&Wip[(size_t)(ng + lrow) * 128 + ko];
        bf16x8 bfr1 = *(const bf16x8*)&Wip[(size_t)(ng + 16 + lrow) * 128 + ko];
        pacc[0] = __builtin_amdgcn_mfma_f32_16x16x32_bf16(afr, bfr0, pacc[0], 0, 0, 0);
        pacc[1] = __builtin_amdgcn_mfma_f32_16x16x32_bf16(afr, bfr1, pacc[1], 0, 0, 0);
      }
#pragma unroll
      for (int nj = 0; nj < 2; ++nj) {
        int col = ng + nj * 16 + lrow;
        float bb = ip_b[col];
#pragma unroll
        for (int r = 0; r < 4; ++r)
          Xs[(mrow0 + q * 4 + r) * LDA + col] = (bf16)(pacc[nj][r] + bb);
      }
    }
  }
  __syncthreads();
  for (int i = t; i < 1024; i += 256) {
    int row = i >> 4; int c8 = (i & 15) << 3;
    *(bf16x8*)&feat2b[(size_t)(m0 + row) * 128 + c8] = *(const bf16x8*)&Fs[row * LDA + c8];
    *(bf16x8*)&xpb[(size_t)(36864 + m0 + row) * 128 + c8] = *(const bf16x8*)&Xs[row * LDA + c8];
  }
}

// ---------------------------------------------------------------------------
// DUAL mid launch: blocks [0,576) = conv2+ip (heavy, starts first);
// [576,2880) = upsample+ip. Disjoint I/O (y2b->feat2b,xpb4-7 vs
// y1b->feat1b,xpb0-3). LDS = union (conv2's 52224 B dominates).
// ---------------------------------------------------------------------------
__global__ __launch_bounds__(256) void mid_dual_kernel(
    const bf16* __restrict__ y1b, const bf16* __restrict__ y2b,
    const bf16* __restrict__ W2b, const float* __restrict__ b2,
    const bf16* __restrict__ Wip, const float* __restrict__ ip_b,
    bf16* __restrict__ feat1b, bf16* __restrict__ feat2b, bf16* __restrict__ xpb)
{
  __shared__ char LB[52224];
  int bid = blockIdx.x;
  if (bid < 576) {
    bf16* As = (bf16*)LB;                 // 64*LDA*2  = 17408 B
    bf16* Bs = (bf16*)(LB + 17408);       // 128*LDA*2 = 34816 B
    conv2_ip_body(As, Bs, y2b, W2b, b2, Wip, ip_b, feat2b, xpb, bid << 6);
  } else {
    bf16* Ds = (bf16*)LB;                 // 16*LDA*2 = 4352 B
    bf16* Xs = (bf16*)(LB + 4352);
    upsample_ip_body(Ds, Xs, y1b, Wip, ip_b, feat1b, xpb, bid - 576);
  }
}

// ---------------------------------------------------------------------------
// FUSED: depthwise 3x3 + bias + LayerNorm + GELU  ->  offset/mask GEMM.
// XCD-chunked swizzle (4608 = 8*576): one image per XCD L2.
// ---------------------------------------------------------------------------
__global__ __launch_bounds__(256) void dwom_kernel(
    const bf16* __restrict__ featb, const float* __restrict__ dw_w,
    const float* __restrict__ dw_b, const float* __restrict__ ln_g,
    const float* __restrict__ ln_b, const bf16* __restrict__ Wom,
    const float* __restrict__ bom, f16* __restrict__ offm)
{
  __shared__ float Wts[1152];   // dw_w [9][128]
  __shared__ float Pb[384];     // dw_b | ln_g | ln_b
  __shared__ bf16 Ds[16 * LDA]; // dwg tile [16px][128ch]
  int t = threadIdx.x;
  for (int i = t; i < 1152; i += 256) Wts[i] = dw_w[i];
  for (int i = t; i < 384; i += 256)
    Pb[i] = (i < 128) ? dw_b[i] : (i < 256 ? ln_g[i - 128] : ln_b[i - 256]);
  __syncthreads();

  int bid = blockIdx.x;
  int wg = (bid & 7) * 576 + (bid >> 3);
  {
    int pxl = t >> 4;
    int c8 = (t & 15) << 3;
    int pixel = wg * 16 + pxl;
    int n = pixel / NPIX; int hw = pixel - n * NPIX;
    int h = hw / 96; int w = hw - h * 96;
    const bf16* fn = featb + (size_t)n * NPIX * 128 + c8;
    bf16x8 zv;
#pragma unroll
    for (int e = 0; e < 8; ++e) zv[e] = (bf16)0.f;

    bf16x8 v[9];
#pragma unroll
    for (int p = 0; p < 9; ++p) {
      int hh = h + p / 3 - 1, ww = w + (p % 3) - 1;
      bool valid = ((unsigned)hh < 96u) && ((unsigned)ww < 96u);
      int hc = min(max(hh, 0), 95), wc = min(max(ww, 0), 95);
      bf16x8 x = *(const bf16x8*)&fn[(hc * 96 + wc) * 128];
      v[p] = valid ? x : zv;
    }

    float acc[8];
#pragma unroll
    for (int e = 0; e < 8; ++e) acc[e] = Pb[c8 + e];
#pragma unroll
    for (int p = 0; p < 9; ++p) {
      f32x4 w0 = *(const f32x4*)&Wts[p * 128 + c8];
      f32x4 w1 = *(const f32x4*)&Wts[p * 128 + c8 + 4];
#pragma unroll
      for (int e = 0; e < 4; ++e) {
        acc[e]     += (float)v[p][e]     * w0[e];
        acc[4 + e] += (float)v[p][4 + e] * w1[e];
      }
    }

    float s = 0.f, qs = 0.f;
#pragma unroll
    for (int e = 0; e < 8; ++e) { s += acc[e]; qs += acc[e] * acc[e]; }
#pragma unroll
    for (int off = 8; off > 0; off >>= 1) {
      s  += __shfl_xor(s, off);
      qs += __shfl_xor(qs, off);
    }
    float mean = s * (1.f / 128.f);
    float var = qs * (1.f / 128.f) - mean * mean;
    float rstd = rsqrtf(var + EPSV);
    bf16x8 o;
#pragma unroll
    for (int e = 0; e < 8; ++e) {
      float xn = (acc[e] - mean) * rstd * Pb[128 + c8 + e] + Pb[256 + c8 + e];
      float z = 0.7978845608028654f * (xn + 0.044715f * xn * xn * xn);
      float th;
      if (z > 15.f) th = 1.f;
      else if (z < -15.f) th = -1.f;
      else { float e2 = __expf(2.f * z); th = (e2 - 1.f) / (e2 + 1.f); }
      o[e] = (bf16)(0.5f * xn * (1.f + th));
    }
    *(bf16x8*)&Ds[pxl * LDA + c8] = o;
  }
  __syncthreads();

  // ---- offset/mask GEMM: Ds[16][128] @ Wom[224][128]^T + bom -> f16 offm
  {
    int wv = t >> 6, lane = t & 63;
    int lrow = lane & 15, q = lane >> 4;
    f16* orow = offm + (size_t)(wg * 16) * 224;
    for (int gsel = wv; gsel < 7; gsel += 4) {
      int n0 = gsel * 32;
      f32x4 pacc[2];
#pragma unroll
      for (int j = 0; j < 2; ++j)
#pragma unroll
        for (int e = 0; e < 4; ++e) pacc[j][e] = 0.f;
#pragma unroll
      for (int ks = 0; ks < 4; ++ks) {
        int ko = ks * 32 + q * 8;
        bf16x8 afr  = *(const bf16x8*)&Ds[lrow * LDA + ko];
        bf16x8 bfr0 = *(const bf16x8*)&Wom[(size_t)(n0 + lrow) * 128 + ko];
        bf16x8 bfr1 = *(const bf16x8*)&Wom[(size_t)(n0 + 16 + lrow) * 128 + ko];
        pacc[0] = __builtin_amdgcn_mfma_f32_16x16x32_bf16(afr, bfr0, pacc[0], 0, 0, 0);
        pacc[1] = __builtin_amdgcn_mfma_f32_16x16x32_bf16(afr, bfr1, pacc[1], 0, 0, 0);
      }
#pragma unroll
      for (int nj = 0; nj < 2; ++nj) {
        int col = n0 + nj * 16 + lrow;
        float bb = bom[col];
#pragma unroll
        for (int r = 0; r < 4; ++r) {
          int px = q * 4 + r;
          orow[(size_t)px * 224 + col] = (f16)(pacc[nj][r] + bb);
        }
      }
    }
  }
}

// ---------------------------------------------------------------------------
// Deformable sampling + output projection, PLUS independent x0 copy riding
// in blocks [2304,4608): sample is latency-bound at 17% HBM, the pure-copy
// blocks stream x0 during its stalls.
// ---------------------------------------------------------------------------
__global__ __launch_bounds__(512, 6) void sample_copy_kernel(
    const bf16* __restrict__ xpb, const f16* __restrict__ offm,
    const bf16* __restrict__ Wop, const float* __restrict__ op_b,
    const float4* __restrict__ x0, float* __restrict__ out)
{
  __shared__ char LB[32256];
  int t = threadIdx.x;
  int bid = blockIdx.x;
  if (bid >= 2304) {
    // ---- x0 copy: 2304 blocks x 512 threads x 1 float4 = 1,179,648
    int idx = (bid - 2304) * 512 + t;
    int n = idx / (128 * 2304);
    int r = idx - n * (128 * 2304);
    float4* outv = (float4*)out;
    outv[(size_t)(n * 384 + 128) * 2304 + r] = x0[(size_t)n * 128 * 2304 + r];
    return;
  }
  uint32_t* Sd = (uint32_t*)LB;                 // 32 px * 224 f16 = 14336 B
  float*    Pm = (float*)(LB + 14336);          // 32 px * 72 f32  =  9216 B
  bf16*     Avs = (bf16*)(LB + 23552);          // [32][LDA] bf16  =  8704 B
  float*    Cs = (float*)LB;                    // [128][33] f32   = 16896 B (aliases Sd/Pm)
  const f16* S = (const f16*)Sd;
  int wg = (bid & 7) * 288 + (bid >> 3);   // XCD-chunked swizzle (2304 = 8*288)
  {
    const uint32_t* src = (const uint32_t*)(offm + (size_t)wg * 32 * 224);
    for (int i = t; i < 3584; i += 512) Sd[i] = src[i];
  }
  __syncthreads();
  if (t < 256) {
    int px = t >> 3, gg = t & 7;
    const f16* L = S + px * 224 + 144 + gg * 9;
    float l[9]; float mx = -1e30f;
#pragma unroll
    for (int p = 0; p < 9; ++p) { l[p] = (float)L[p]; mx = fmaxf(mx, l[p]); }
    float se = 0.f;
#pragma unroll
    for (int p = 0; p < 9; ++p) { l[p] = __expf(l[p] - mx); se += l[p]; }
    float inv = 1.f / se;
    float* Pp = Pm + px * 72 + gg * 9;
#pragma unroll
    for (int p = 0; p < 9; ++p) Pp[p] = l[p] * inv;
  }
  __syncthreads();
  {
    int pxl = t >> 4;                       // 0..31
    int tid16 = t & 15;
    int g = tid16 >> 1;
    int c8 = (tid16 & 1) << 3;
    int pixel = wg * 32 + pxl;
    int n = pixel / NPIX; int hw = pixel - n * NPIX;
    int h = hw / 96; int w = hw - h * 96;
    const f16* Sp = S + pxl * 224 + g * 18;
    const float* Pp = Pm + pxl * 72 + g * 9;
    const bf16* xpn = xpb + (size_t)n * NPIX * 128 + g * 16 + c8;
    float acc[8];
#pragma unroll
    for (int e = 0; e < 8; ++e) acc[e] = 0.f;
#pragma unroll 1
    for (int kh = 0; kh < 3; ++kh) {
#pragma unroll
      for (int kw = 0; kw < 3; ++kw) {
        int p = kh * 3 + kw;
        f16x2 d2 = *(const f16x2*)&Sp[p * 2];   // 4B-aligned (even index)
        float dx = (float)d2.x, dy = (float)d2.y;
        float pyu = (float)(h + kh - 1) + dy;
        float pxu = (float)(w + kw - 1) + dx;
        float yf = floorf(pyu), xf = floorf(pxu);
        float wy = pyu - yf, wx = pxu - xf;
        int y0 = (int)yf, x0i = (int)xf;
        float ay0 = ((unsigned)y0 < 96u) ? (1.f - wy) : 0.f;
        float ay1 = ((unsigned)(y0 + 1) < 96u) ? wy : 0.f;
        float ax0 = ((unsigned)x0i < 96u) ? (1.f - wx) : 0.f;
        float ax1 = ((unsigned)(x0i + 1) < 96u) ? wx : 0.f;
        int y0c = min(max(y0, 0), 95), y1c = min(max(y0 + 1, 0), 95);
        int x0c = min(max(x0i, 0), 95), x1c = min(max(x0i + 1, 0), 95);
        float mp = Pp[p];
        float w00 = ay0 * ax0 * mp, w01 = ay0 * ax1 * mp;
        float w10 = ay1 * ax0 * mp, w11 = ay1 * ax1 * mp;
        bf16x8 v00 = *(const bf16x8*)&xpn[(y0c * 96 + x0c) * 128];
        bf16x8 v01 = *(const bf16x8*)&xpn[(y0c * 96 + x1c) * 128];
        bf16x8 v10 = *(const bf16x8*)&xpn[(y1c * 96 + x0c) * 128];
        bf16x8 v11 = *(const bf16x8*)&xpn[(y1c * 96 + x1c) * 128];
#pragma unroll
        for (int e = 0; e < 8; ++e) {
          acc[e] += w00 * (float)v00[e] + w01 * (float)v01[e]
                  + w10 * (float)v10[e] + w11 * (float)v11[e];
        }
      }
    }
    bf16x8 o;
#pragma unroll
    for (int e = 0; e < 8; ++e) o[e] = (bf16)acc[e];
    *(bf16x8*)&Avs[pxl * LDA + g * 16 + c8] = o;
  }
  __syncthreads();

  // ---- fused output projection: Avs[32][128] @ Wop[128][128]^T + op_b, ReLU
  {
    int wv = t >> 6, lane = t & 63;
    int lrow = lane & 15, q = lane >> 4;
    int mrow0 = (wv & 1) * 16;          // which 16-px half
    int n0 = (wv >> 1) * 32;            // 4 col-groups of 32
    f32x4 pacc[2];
#pragma unroll
    for (int j = 0; j < 2; ++j)
#pragma unroll
      for (int e = 0; e < 4; ++e) pacc[j][e] = 0.f;
#pragma unroll
    for (int ks = 0; ks < 4; ++ks) {
      int ko = ks * 32 + q * 8;
      bf16x8 afr  = *(const bf16x8*)&Avs[(mrow0 + lrow) * LDA + ko];
      bf16x8 bfr0 = *(const bf16x8*)&Wop[(size_t)(n0 + lrow) * 128 + ko];
      bf16x8 bfr1 = *(const bf16x8*)&Wop[(size_t)(n0 + 16 + lrow) * 128 + ko];
      pacc[0] = __builtin_amdgcn_mfma_f32_16x16x32_bf16(afr, bfr0, pacc[0], 0, 0, 0);
      pacc[1] = __builtin_amdgcn_mfma_f32_16x16x32_bf16(afr, bfr1, pacc[1], 0, 0, 0);
    }
#pragma unroll
    for (int nj = 0; nj < 2; ++nj) {
      int col = n0 + nj * 16 + lrow;
      float bb = op_b[col];
#pragma unroll
      for (int r = 0; r < 4; ++r) {
        int px = mrow0 + q * 4 + r;
        Cs[col * 33 + px] = fmaxf(pacc[nj][r] + bb, 0.f);
      }
    }
  }
  __syncthreads();

  // ---- coalesced NCHW store: 8 lanes cover one channel's 128B (32 px)
  {
    int nn = (wg * 32) / NPIX;           // all 32 px share one image
    int hwb = wg * 32 - nn * NPIX;
    int img = nn & 3; int choff = (nn >= 4) ? 256 : 0;
    float* ob = out + (size_t)(img * 384 + choff) * NPIX + hwb;
#pragma unroll
    for (int i = t; i < 1024; i += 512) {
      int col = i >> 3, f4 = i & 7;
      f32x4 v = *(const f32x4*)&Cs[col * 33 + f4 * 4];
      *(f32x4*)&ob[(size_t)col * NPIX + f4 * 4] = v;
    }
  }
}

// ---------------------------------------------------------------------------
extern "C" void kernel_launch(void* const* d_in, const int* in_sizes, int n_in,
                              void* d_out, int out_size, void* d_ws, size_t ws_size,
                              hipStream_t stream)
{
  (void)in_sizes; (void)n_in; (void)out_size; (void)ws_size;
  const float* x0      = (const float*)d_in[0];
  const float* x1      = (const float*)d_in[1];
  const float* x2      = (const float*)d_in[2];
  const float* conv_w  = (const float*)d_in[3];
  const float* conv_g  = (const float*)d_in[4];
  const float* conv_b  = (const float*)d_in[5];
  const float* conv_rm = (const float*)d_in[6];
  const float* conv_rv = (const float*)d_in[7];
  const float* conv1_w = (const float*)d_in[8];
  const float* conv1_g = (const float*)d_in[9];
  const float* conv1_b = (const float*)d_in[10];
  const float* conv1_rm= (const float*)d_in[11];
  const float* conv1_rv= (const float*)d_in[12];
  const float* conv2_w = (const float*)d_in[13];
  const float* conv2_g = (const float*)d_in[14];
  const float* conv2_b = (const float*)d_in[15];
  const float* conv2_rm= (const float*)d_in[16];
  const float* conv2_rv= (const float*)d_in[17];
  const float* dw_w    = (const float*)d_in[18];
  const float* dw_b    = (const float*)d_in[19];
  const float* ln_g    = (const float*)d_in[20];
  const float* ln_b    = (const float*)d_in[21];
  const float* off_w   = (const float*)d_in[22];
  const float* off_b   = (const float*)d_in[23];
  const float* m_w     = (const float*)d_in[24];
  const float* m_b     = (const float*)d_in[25];
  const float* ip_w    = (const float*)d_in[26];
  const float* ip_b    = (const float*)d_in[27];
  const float* op_w    = (const float*)d_in[28];
  const float* op_b    = (const float*)d_in[29];
  float* out = (float*)d_out;
  char* WS = (char*)d_ws;

  // byte layout (high-water ~110.9 MB < 125.5 MB workspace)
  // 0         featb   18.9 MB   (imgs 0-3 = feat1b, imgs 4-7 = feat2b)
  // 18874368  y2b     37.7 MB
  // 56623104  y1b      2.36 MB
  // 58982400  offm    33.0 MB   (f16 73728x224)
  // 92012544  xpb     18.9 MB   (NO overlap with y2b)
  // 125042688 WTSf / WTSb
  bf16* featb  = (bf16*)WS;
  bf16* feat1b = featb;
  bf16* feat2b = featb + 4718592;
  bf16* y2b    = (bf16*)(WS + 18874368);
  bf16* y1b    = (bf16*)(WS + 56623104);
  f16*  offm   = (f16*)(WS + 58982400);
  bf16* xpb    = (bf16*)(WS + 92012544);
  float* WTSf  = (float*)(WS + 125042688);       // 608 floats
  bf16*  WTSb  = (bf16*)(WS + 125045120);        // 249856 bf16

  float* b1f  = WTSf;
  float* b1bf = WTSf + 128;
  float* b2f  = WTSf + 256;
  float* bomf = WTSf + 384;
  bf16* W1b  = WTSb;
  bf16* W1bb = WTSb + 32768;
  bf16* W2b  = WTSb + 40960;
  bf16* Wipb = WTSb + 188416;
  bf16* Womb = WTSb + 204800;
  bf16* Wopb = WTSb + 233472;

  prep_kernel<<<979, 256, 0, stream>>>(
      conv_w, conv_g, conv_b, conv_rm, conv_rv,
      conv1_w, conv1_g, conv1_b, conv1_rm, conv1_rv,
      conv2_w, conv2_g, conv2_b, conv2_rm, conv2_rv,
      ip_w, op_w, off_w, m_w, off_b, m_b, WTSf, WTSb);

  // both 1x1 convs in one launch (x2: 2304 blocks, x1: 144 blocks)
  c1x1_dual_kernel<<<2448, 256, 0, stream>>>(x1, W1b, b1f, x2, W1bb, b1bf, y1b, y2b);

  // conv2+ip (576) || upsample+ip (2304) in one launch
  mid_dual_kernel<<<2880, 256, 0, stream>>>(y1b, y2b, W2b, b2f, Wipb, ip_b,
                                            feat1b, feat2b, xpb);

  // fused dual-branch DCNv3 (M = 73728)
  dwom_kernel<<<4608, 256, 0, stream>>>(featb, dw_w, dw_b, ln_g, ln_b, Womb, bomf, offm);

  // sample+op-proj (2304) || x0 copy (2304) in one launch
  sample_copy_kernel<<<4608, 512, 0, stream>>>(xpb, offm, Wopb, op_b,
                                               (const float4*)x0, out);
}

// Round 11
// 355.506 us; speedup vs baseline: 1.0627x; 1.0627x over previous
//
#include <hip/hip_runtime.h>
#include <cstdint>
#include <cstddef>

#define EPSV 1e-5f
#define NPIX 9216          // 96*96
#define LDA 136            // padded bf16 k-stride for 128-wide K chunks
#define LDK 72             // padded bf16 k-stride for 64-wide K chunks

typedef __bf16 bf16;
typedef _Float16 f16;
typedef __attribute__((ext_vector_type(8))) __bf16 bf16x8;
typedef __attribute__((ext_vector_type(4))) __bf16 bf16x4;
typedef __attribute__((ext_vector_type(2))) _Float16 f16x2;
typedef __attribute__((ext_vector_type(4))) float  f32x4;

__device__ __forceinline__ float silu_f(float v) { return v / (1.f + __expf(-v)); }

// ---------------------------------------------------------------------------
// WTSf (float, 608): b1[128] | b1b[128] | b2[128] | bom[224]
// WTSb (bf16, 249856), all [co][ci]:
//   0       W1b  [128][256]  (x1 1x1, BN-folded)
//   32768   W1bb [128][64]   (x2 1x1, BN-folded)
//   40960   W2b  [9][128][128] (3x3 s2, BN-folded, k-major)
//   188416  Wipb [128][128]
//   204800  Womb [224][128]  (rows 216..223 zero)
//   233472  Wopb [128][128]
// ---------------------------------------------------------------------------
__global__ __launch_bounds__(256) void prep_kernel(
    const float* __restrict__ conv_w, const float* __restrict__ conv_g,
    const float* __restrict__ conv_b, const float* __restrict__ conv_rm, const float* __restrict__ conv_rv,
    const float* __restrict__ conv1_w, const float* __restrict__ conv1_g,
    const float* __restrict__ conv1_b, const float* __restrict__ conv1_rm, const float* __restrict__ conv1_rv,
    const float* __restrict__ conv2_w, const float* __restrict__ conv2_g,
    const float* __restrict__ conv2_bb, const float* __restrict__ conv2_rm, const float* __restrict__ conv2_rv,
    const float* __restrict__ ip_w, const float* __restrict__ op_w,
    const float* __restrict__ off_w, const float* __restrict__ m_w,
    const float* __restrict__ off_b, const float* __restrict__ m_b,
    float* __restrict__ WTSf, bf16* __restrict__ WTSb)
{
  int idx = blockIdx.x * 256 + threadIdx.x;
  if (idx < 608) {
    if (idx < 128) {
      int co = idx;
      float s = conv_g[co] * rsqrtf(conv_rv[co] + EPSV);
      WTSf[idx] = conv_b[co] - conv_rm[co] * s;
    } else if (idx < 256) {
      int co = idx - 128;
      float s = conv1_g[co] * rsqrtf(conv1_rv[co] + EPSV);
      WTSf[idx] = conv1_b[co] - conv1_rm[co] * s;
    } else if (idx < 384) {
      int co = idx - 256;
      float s = conv2_g[co] * rsqrtf(conv2_rv[co] + EPSV);
      WTSf[idx] = conv2_bb[co] - conv2_rm[co] * s;
    } else {
      int col = idx - 384;
      WTSf[idx] = (col < 144) ? off_b[col] : (col < 216 ? m_b[col - 144] : 0.f);
    }
  } else {
    int j = idx - 608;
    if (j < 32768) {
      int co = j >> 8, ci = j & 255;
      float s = conv_g[co] * rsqrtf(conv_rv[co] + EPSV);
      WTSb[j] = (bf16)(conv_w[co * 256 + ci] * s);
    } else if (j < 40960) {
      int r = j - 32768; int co = r >> 6, ci = r & 63;
      float s = conv1_g[co] * rsqrtf(conv1_rv[co] + EPSV);
      WTSb[j] = (bf16)(conv1_w[co * 64 + ci] * s);
    } else if (j < 188416) {
      int r = j - 40960; int kp = r >> 14; int rr = r & 16383;
      int co = rr >> 7, ci = rr & 127;
      float s = conv2_g[co] * rsqrtf(conv2_rv[co] + EPSV);
      WTSb[j] = (bf16)(conv2_w[(co * 128 + ci) * 9 + kp] * s);
    } else if (j < 204800) {
      int r = j - 188416; int co = r >> 7, ci = r & 127;
      WTSb[j] = (bf16)ip_w[co * 128 + ci];
    } else if (j < 233472) {
      int r = j - 204800; int co = r >> 7, ci = r & 127;
      float v = (co < 144) ? off_w[co * 128 + ci] : (co < 216 ? m_w[(co - 144) * 128 + ci] : 0.f);
      WTSb[j] = (bf16)v;
    } else if (j < 249856) {
      int r = j - 233472; int co = r >> 7, ci = r & 127;
      WTSb[j] = (bf16)op_w[co * 128 + ci];
    }
  }
}

// ---------------------------------------------------------------------------
// 1x1 conv body via MFMA: NCHW fp32 (K ch) -> NHWC bf16 (128 ch) + BN + SiLU
// ---------------------------------------------------------------------------
__device__ __forceinline__ void c1x1_body(
    bf16* As, bf16* Bs, const float* __restrict__ x, const bf16* __restrict__ W,
    const float* __restrict__ bias, int K, int HW, int m0, bf16* __restrict__ outb)
{
  int t = threadIdx.x;
  int n = m0 / HW; int hw0 = m0 - n * HW;
  const float* xn = x + (size_t)n * K * HW;
  int wv = t >> 6, lane = t & 63;
  int lrow = lane & 15, q = lane >> 4;
  int n0 = wv * 32;
  f32x4 acc[4][2];
#pragma unroll
  for (int i = 0; i < 4; ++i)
#pragma unroll
    for (int j = 0; j < 2; ++j)
#pragma unroll
      for (int e = 0; e < 4; ++e) acc[i][j][e] = 0.f;

  for (int k0 = 0; k0 < K; k0 += 64) {
    if (k0) __syncthreads();
    for (int i = t; i < 1024; i += 256) {
      int px = i & 63; int ci4 = (i >> 6) << 2;
      bf16x4 p;
#pragma unroll
      for (int j = 0; j < 4; ++j)
        p[j] = (bf16)xn[(size_t)(k0 + ci4 + j) * HW + hw0 + px];
      *(bf16x4*)&As[px * LDK + ci4] = p;
    }
    for (int i = t; i < 1024; i += 256) {
      int co = i >> 3; int k8 = (i & 7) << 3;
      *(bf16x8*)&Bs[co * LDK + k8] = *(const bf16x8*)&W[(size_t)co * K + k0 + k8];
    }
    __syncthreads();
#pragma unroll
    for (int ks = 0; ks < 2; ++ks) {
      int ko = ks * 32 + q * 8;
      bf16x8 bfr0 = *(const bf16x8*)&Bs[(n0 + lrow) * LDK + ko];
      bf16x8 bfr1 = *(const bf16x8*)&Bs[(n0 + 16 + lrow) * LDK + ko];
#pragma unroll
      for (int mi = 0; mi < 4; ++mi) {
        bf16x8 afr = *(const bf16x8*)&As[(mi * 16 + lrow) * LDK + ko];
        acc[mi][0] = __builtin_amdgcn_mfma_f32_16x16x32_bf16(afr, bfr0, acc[mi][0], 0, 0, 0);
        acc[mi][1] = __builtin_amdgcn_mfma_f32_16x16x32_bf16(afr, bfr1, acc[mi][1], 0, 0, 0);
      }
    }
  }
#pragma unroll
  for (int mi = 0; mi < 4; ++mi) {
#pragma unroll
    for (int nj = 0; nj < 2; ++nj) {
      int co = n0 + nj * 16 + lrow;
      float bb = bias[co];
#pragma unroll
      for (int r = 0; r < 4; ++r) {
        int m = m0 + mi * 16 + q * 4 + r;
        outb[(size_t)m * 128 + co] = (bf16)silu_f(acc[mi][nj][r] + bb);
      }
    }
  }
}

// ---------------------------------------------------------------------------
// DUAL 1x1 conv launch: blocks [0,2304) = x2 path (K=64), [2304,2448) = x1
// path (K=256). Independent I/O; packs the 144-block x1 conv into the x2
// conv's shadow.
// ---------------------------------------------------------------------------
__global__ __launch_bounds__(256) void c1x1_dual_kernel(
    const float* __restrict__ x1, const bf16* __restrict__ W1b, const float* __restrict__ b1f,
    const float* __restrict__ x2, const bf16* __restrict__ W1bb, const float* __restrict__ b1bf,
    bf16* __restrict__ y1b, bf16* __restrict__ y2b)
{
  __shared__ bf16 As[64 * LDK];
  __shared__ bf16 Bs[128 * LDK];
  int bid = blockIdx.x;
  if (bid < 2304) {
    c1x1_body(As, Bs, x2, W1bb, b1bf, 64, 36864, bid << 6, y2b);
  } else {
    c1x1_body(As, Bs, x1, W1b, b1f, 256, 2304, (bid - 2304) << 6, y1b);
  }
}

// ---------------------------------------------------------------------------
// bilinear 2x upsample, NHWC bf16 -> bf16 ; thread = 4 channels  (R7 version)
// ---------------------------------------------------------------------------
__global__ __launch_bounds__(256) void upsample_kernel(
    const bf16* __restrict__ y1b, bf16* __restrict__ feat1b)
{
  int idx = blockIdx.x * 256 + threadIdx.x;   // 1,179,648 total
  int c4 = (idx & 31) << 2;
  int pw = idx >> 5;
  int ow = pw % 96; int t1 = pw / 96;
  int oh = t1 % 96; int n = t1 / 96;
  float sh = oh * 0.5f - 0.25f, sw = ow * 0.5f - 0.25f;
  float hf = floorf(sh), wf = floorf(sw);
  float fy = sh - hf, fx = sw - wf;
  int h0 = (int)hf, w0 = (int)wf;
  int h0c = max(h0, 0), h1c = min(h0 + 1, 47);
  int w0c = max(w0, 0), w1c = min(w0 + 1, 47);
  const bf16* yn = y1b + (size_t)n * 2304 * 128 + c4;
  bf16x4 v00 = *(const bf16x4*)&yn[(h0c * 48 + w0c) * 128];
  bf16x4 v01 = *(const bf16x4*)&yn[(h0c * 48 + w1c) * 128];
  bf16x4 v10 = *(const bf16x4*)&yn[(h1c * 48 + w0c) * 128];
  bf16x4 v11 = *(const bf16x4*)&yn[(h1c * 48 + w1c) * 128];
  bf16x4 o;
#pragma unroll
  for (int e = 0; e < 4; ++e) {
    float v = (1.f - fy) * ((1.f - fx) * (float)v00[e] + fx * (float)v01[e])
            + fy * ((1.f - fx) * (float)v10[e] + fx * (float)v11[e]);
    o[e] = (bf16)v;
  }
  *(bf16x4*)&feat1b[((size_t)n * NPIX + oh * 96 + ow) * 128 + c4] = o;
}

// ---------------------------------------------------------------------------
// conv2 via MFMA: 3x3 s2 p1 + BN + SiLU. y2b NHWC bf16 -> feat2b.  (R7 ver.)
// ---------------------------------------------------------------------------
__global__ __launch_bounds__(256) void conv2_mfma_kernel(
    const bf16* __restrict__ y2b, const bf16* __restrict__ W2b,
    const float* __restrict__ b2, bf16* __restrict__ feat2b)
{
  __shared__ bf16 As[64 * LDA];
  __shared__ bf16 Bs[128 * LDA];
  int m0 = blockIdx.x << 6;
  int t = threadIdx.x;
  int wv = t >> 6, lane = t & 63;
  int lrow = lane & 15, q = lane >> 4;
  int n0 = wv * 32;
  f32x4 acc[4][2];
#pragma unroll
  for (int i = 0; i < 4; ++i)
#pragma unroll
    for (int j = 0; j < 2; ++j)
#pragma unroll
      for (int e = 0; e < 4; ++e) acc[i][j][e] = 0.f;
  bf16x8 zv;
#pragma unroll
  for (int e = 0; e < 8; ++e) zv[e] = (bf16)0.f;

  for (int kp = 0; kp < 9; ++kp) {
    int kh = kp / 3, kw = kp - kh * 3;
    __syncthreads();
    for (int i = t; i < 1024; i += 256) {
      int row = i >> 4; int c8 = (i & 15) << 3;
      int m = m0 + row;
      int nimg = m / NPIX; int hw = m - nimg * NPIX;
      int oh = hw / 96, ow = hw - oh * 96;
      int ih = 2 * oh - 1 + kh, iw = 2 * ow - 1 + kw;
      bf16x8 v = zv;
      if ((unsigned)ih < 192u && (unsigned)iw < 192u)
        v = *(const bf16x8*)&y2b[(((size_t)nimg * 192 + ih) * 192 + iw) * 128 + c8];
      *(bf16x8*)&As[row * LDA + c8] = v;
    }
    const bf16* Wk = W2b + kp * 16384;
    for (int i = t; i < 2048; i += 256) {
      int nn = i >> 4; int k8 = (i & 15) << 3;
      *(bf16x8*)&Bs[nn * LDA + k8] = *(const bf16x8*)&Wk[nn * 128 + k8];
    }
    __syncthreads();
#pragma unroll
    for (int ks = 0; ks < 4; ++ks) {
      bf16x8 bfr0 = *(const bf16x8*)&Bs[(n0 + lrow) * LDA + ks * 32 + q * 8];
      bf16x8 bfr1 = *(const bf16x8*)&Bs[(n0 + 16 + lrow) * LDA + ks * 32 + q * 8];
#pragma unroll
      for (int mi = 0; mi < 4; ++mi) {
        bf16x8 afr = *(const bf16x8*)&As[(mi * 16 + lrow) * LDA + ks * 32 + q * 8];
        acc[mi][0] = __builtin_amdgcn_mfma_f32_16x16x32_bf16(afr, bfr0, acc[mi][0], 0, 0, 0);
        acc[mi][1] = __builtin_amdgcn_mfma_f32_16x16x32_bf16(afr, bfr1, acc[mi][1], 0, 0, 0);
      }
    }
  }
#pragma unroll
  for (int mi = 0; mi < 4; ++mi) {
#pragma unroll
    for (int nj = 0; nj < 2; ++nj) {
      int co = n0 + nj * 16 + lrow;
      float bb = b2[co];
#pragma unroll
      for (int r = 0; r < 4; ++r) {
        int m = m0 + mi * 16 + q * 4 + r;
        feat2b[(size_t)m * 128 + co] = (bf16)silu_f(acc[mi][nj][r] + bb);
      }
    }
  }
}

// ---------------------------------------------------------------------------
// ip GEMM: A bf16 [M][128] @ Wip[128][128]^T + ip_b -> bf16 xpb  (R7 mm,
// store_mode 2 specialization)
// ---------------------------------------------------------------------------
__global__ __launch_bounds__(256) void mm_ip_kernel(
    const bf16* __restrict__ A, const bf16* __restrict__ W,
    const float* __restrict__ bias, bf16* __restrict__ outb)
{
  __shared__ bf16 As[64 * LDA];
  __shared__ bf16 Bs[128 * LDA];
  int m0 = blockIdx.x << 6;
  int t = threadIdx.x;
  for (int i = t; i < 1024; i += 256) {
    int row = i >> 4; int c8 = (i & 15) << 3;
    *(bf16x8*)&As[row * LDA + c8] = *(const bf16x8*)&A[(size_t)(m0 + row) * 128 + c8];
  }
  for (int i = t; i < 2048; i += 256) {
    int n = i >> 4; int k8 = (i & 15) << 3;
    *(bf16x8*)&Bs[n * LDA + k8] = *(const bf16x8*)&W[(size_t)n * 128 + k8];
  }
  __syncthreads();

  int wv = t >> 6, lane = t & 63;
  int lrow = lane & 15, q = lane >> 4;
  int n0 = wv * 32;
  f32x4 acc[4][2];
#pragma unroll
  for (int i = 0; i < 4; ++i)
#pragma unroll
    for (int j = 0; j < 2; ++j)
#pragma unroll
      for (int e = 0; e < 4; ++e) acc[i][j][e] = 0.f;

#pragma unroll
  for (int ks = 0; ks < 4; ++ks) {
    bf16x8 bfr0 = *(const bf16x8*)&Bs[(n0 + lrow) * LDA + ks * 32 + q * 8];
    bf16x8 bfr1 = *(const bf16x8*)&Bs[(n0 + 16 + lrow) * LDA + ks * 32 + q * 8];
#pragma unroll
    for (int mi = 0; mi < 4; ++mi) {
      bf16x8 afr = *(const bf16x8*)&As[(mi * 16 + lrow) * LDA + ks * 32 + q * 8];
      acc[mi][0] = __builtin_amdgcn_mfma_f32_16x16x32_bf16(afr, bfr0, acc[mi][0], 0, 0, 0);
      acc[mi][1] = __builtin_amdgcn_mfma_f32_16x16x32_bf16(afr, bfr1, acc[mi][1], 0, 0, 0);
    }
  }
#pragma unroll
  for (int mi = 0; mi < 4; ++mi) {
#pragma unroll
    for (int nj = 0; nj < 2; ++nj) {
      int col = n0 + nj * 16 + lrow;
      float bb = bias[col];
#pragma unroll
      for (int r = 0; r < 4; ++r) {
        int m = m0 + mi * 16 + q * 4 + r;
        outb[(size_t)m * 128 + col] = (bf16)(acc[mi][nj][r] + bb);
      }
    }
  }
}

// ---------------------------------------------------------------------------
// FUSED: depthwise 3x3 + bias + LayerNorm + GELU  ->  offset/mask GEMM.
// XCD-chunked swizzle (4608 = 8*576): one image per XCD L2.
// ---------------------------------------------------------------------------
__global__ __launch_bounds__(256) void dwom_kernel(
    const bf16* __restrict__ featb, const float* __restrict__ dw_w,
    const float* __restrict__ dw_b, const float* __restrict__ ln_g,
    const float* __restrict__ ln_b, const bf16* __restrict__ Wom,
    const float* __restrict__ bom, f16* __restrict__ offm)
{
  __shared__ float Wts[1152];   // dw_w [9][128]
  __shared__ float Pb[384];     // dw_b | ln_g | ln_b
  __shared__ bf16 Ds[16 * LDA]; // dwg tile [16px][128ch]
  int t = threadIdx.x;
  for (int i = t; i < 1152; i += 256) Wts[i] = dw_w[i];
  for (int i = t; i < 384; i += 256)
    Pb[i] = (i < 128) ? dw_b[i] : (i < 256 ? ln_g[i - 128] : ln_b[i - 256]);
  __syncthreads();

  int bid = blockIdx.x;
  int wg = (bid & 7) * 576 + (bid >> 3);
  {
    int pxl = t >> 4;
    int c8 = (t & 15) << 3;
    int pixel = wg * 16 + pxl;
    int n = pixel / NPIX; int hw = pixel - n * NPIX;
    int h = hw / 96; int w = hw - h * 96;
    const bf16* fn = featb + (size_t)n * NPIX * 128 + c8;
    bf16x8 zv;
#pragma unroll
    for (int e = 0; e < 8; ++e) zv[e] = (bf16)0.f;

    bf16x8 v[9];
#pragma unroll
    for (int p = 0; p < 9; ++p) {
      int hh = h + p / 3 - 1, ww = w + (p % 3) - 1;
      bool valid = ((unsigned)hh < 96u) && ((unsigned)ww < 96u);
      int hc = min(max(hh, 0), 95), wc = min(max(ww, 0), 95);
      bf16x8 x = *(const bf16x8*)&fn[(hc * 96 + wc) * 128];
      v[p] = valid ? x : zv;
    }

    float acc[8];
#pragma unroll
    for (int e = 0; e < 8; ++e) acc[e] = Pb[c8 + e];
#pragma unroll
    for (int p = 0; p < 9; ++p) {
      f32x4 w0 = *(const f32x4*)&Wts[p * 128 + c8];
      f32x4 w1 = *(const f32x4*)&Wts[p * 128 + c8 + 4];
#pragma unroll
      for (int e = 0; e < 4; ++e) {
        acc[e]     += (float)v[p][e]     * w0[e];
        acc[4 + e] += (float)v[p][4 + e] * w1[e];
      }
    }

    float s = 0.f, qs = 0.f;
#pragma unroll
    for (int e = 0; e < 8; ++e) { s += acc[e]; qs += acc[e] * acc[e]; }
#pragma unroll
    for (int off = 8; off > 0; off >>= 1) {
      s  += __shfl_xor(s, off);
      qs += __shfl_xor(qs, off);
    }
    float mean = s * (1.f / 128.f);
    float var = qs * (1.f / 128.f) - mean * mean;
    float rstd = rsqrtf(var + EPSV);
    bf16x8 o;
#pragma unroll
    for (int e = 0; e < 8; ++e) {
      float xn = (acc[e] - mean) * rstd * Pb[128 + c8 + e] + Pb[256 + c8 + e];
      float z = 0.7978845608028654f * (xn + 0.044715f * xn * xn * xn);
      float th;
      if (z > 15.f) th = 1.f;
      else if (z < -15.f) th = -1.f;
      else { float e2 = __expf(2.f * z); th = (e2 - 1.f) / (e2 + 1.f); }
      o[e] = (bf16)(0.5f * xn * (1.f + th));
    }
    *(bf16x8*)&Ds[pxl * LDA + c8] = o;
  }
  __syncthreads();

  // ---- offset/mask GEMM: Ds[16][128] @ Wom[224][128]^T + bom -> f16 offm
  {
    int wv = t >> 6, lane = t & 63;
    int lrow = lane & 15, q = lane >> 4;
    f16* orow = offm + (size_t)(wg * 16) * 224;
    for (int gsel = wv; gsel < 7; gsel += 4) {
      int n0 = gsel * 32;
      f32x4 pacc[2];
#pragma unroll
      for (int j = 0; j < 2; ++j)
#pragma unroll
        for (int e = 0; e < 4; ++e) pacc[j][e] = 0.f;
#pragma unroll
      for (int ks = 0; ks < 4; ++ks) {
        int ko = ks * 32 + q * 8;
        bf16x8 afr  = *(const bf16x8*)&Ds[lrow * LDA + ko];
        bf16x8 bfr0 = *(const bf16x8*)&Wom[(size_t)(n0 + lrow) * 128 + ko];
        bf16x8 bfr1 = *(const bf16x8*)&Wom[(size_t)(n0 + 16 + lrow) * 128 + ko];
        pacc[0] = __builtin_amdgcn_mfma_f32_16x16x32_bf16(afr, bfr0, pacc[0], 0, 0, 0);
        pacc[1] = __builtin_amdgcn_mfma_f32_16x16x32_bf16(afr, bfr1, pacc[1], 0, 0, 0);
      }
#pragma unroll
      for (int nj = 0; nj < 2; ++nj) {
        int col = n0 + nj * 16 + lrow;
        float bb = bom[col];
#pragma unroll
        for (int r = 0; r < 4; ++r) {
          int px = q * 4 + r;
          orow[(size_t)px * 224 + col] = (f16)(pacc[nj][r] + bb);
        }
      }
    }
  }
}

// ---------------------------------------------------------------------------
// Deformable sampling + output projection, PLUS independent x0 copy riding
// in blocks [2304,4608): sample is latency-bound at ~17% HBM, the pure-copy
// blocks stream x0 during its stalls.
// ---------------------------------------------------------------------------
__global__ __launch_bounds__(512, 6) void sample_copy_kernel(
    const bf16* __restrict__ xpb, const f16* __restrict__ offm,
    const bf16* __restrict__ Wop, const float* __restrict__ op_b,
    const float4* __restrict__ x0, float* __restrict__ out)
{
  __shared__ char LB[32256];
  int t = threadIdx.x;
  int bid = blockIdx.x;
  if (bid >= 2304) {
    // ---- x0 copy: 2304 blocks x 512 threads x 1 float4 = 1,179,648
    int idx = (bid - 2304) * 512 + t;
    int n = idx / (128 * 2304);
    int r = idx - n * (128 * 2304);
    float4* outv = (float4*)out;
    outv[(size_t)(n * 384 + 128) * 2304 + r] = x0[(size_t)n * 128 * 2304 + r];
    return;
  }
  uint32_t* Sd = (uint32_t*)LB;                 // 32 px * 224 f16 = 14336 B
  float*    Pm = (float*)(LB + 14336);          // 32 px * 72 f32  =  9216 B
  bf16*     Avs = (bf16*)(LB + 23552);          // [32][LDA] bf16  =  8704 B
  float*    Cs = (float*)LB;                    // [128][33] f32   = 16896 B (aliases Sd/Pm)
  const f16* S = (const f16*)Sd;
  int wg = (bid & 7) * 288 + (bid >> 3);   // XCD-chunked swizzle (2304 = 8*288)
  {
    const uint32_t* src = (const uint32_t*)(offm + (size_t)wg * 32 * 224);
    for (int i = t; i < 3584; i += 512) Sd[i] = src[i];
  }
  __syncthreads();
  if (t < 256) {
    int px = t >> 3, gg = t & 7;
    const f16* L = S + px * 224 + 144 + gg * 9;
    float l[9]; float mx = -1e30f;
#pragma unroll
    for (int p = 0; p < 9; ++p) { l[p] = (float)L[p]; mx = fmaxf(mx, l[p]); }
    float se = 0.f;
#pragma unroll
    for (int p = 0; p < 9; ++p) { l[p] = __expf(l[p] - mx); se += l[p]; }
    float inv = 1.f / se;
    float* Pp = Pm + px * 72 + gg * 9;
#pragma unroll
    for (int p = 0; p < 9; ++p) Pp[p] = l[p] * inv;
  }
  __syncthreads();
  {
    int pxl = t >> 4;                       // 0..31
    int tid16 = t & 15;
    int g = tid16 >> 1;
    int c8 = (tid16 & 1) << 3;
    int pixel = wg * 32 + pxl;
    int n = pixel / NPIX; int hw = pixel - n * NPIX;
    int h = hw / 96; int w = hw - h * 96;
    const f16* Sp = S + pxl * 224 + g * 18;
    const float* Pp = Pm + pxl * 72 + g * 9;
    const bf16* xpn = xpb + (size_t)n * NPIX * 128 + g * 16 + c8;
    float acc[8];
#pragma unroll
    for (int e = 0; e < 8; ++e) acc[e] = 0.f;
#pragma unroll 1
    for (int kh = 0; kh < 3; ++kh) {
#pragma unroll
      for (int kw = 0; kw < 3; ++kw) {
        int p = kh * 3 + kw;
        f16x2 d2 = *(const f16x2*)&Sp[p * 2];   // 4B-aligned (even index)
        float dx = (float)d2.x, dy = (float)d2.y;
        float pyu = (float)(h + kh - 1) + dy;
        float pxu = (float)(w + kw - 1) + dx;
        float yf = floorf(pyu), xf = floorf(pxu);
        float wy = pyu - yf, wx = pxu - xf;
        int y0 = (int)yf, x0i = (int)xf;
        float ay0 = ((unsigned)y0 < 96u) ? (1.f - wy) : 0.f;
        float ay1 = ((unsigned)(y0 + 1) < 96u) ? wy : 0.f;
        float ax0 = ((unsigned)x0i < 96u) ? (1.f - wx) : 0.f;
        float ax1 = ((unsigned)(x0i + 1) < 96u) ? wx : 0.f;
        int y0c = min(max(y0, 0), 95), y1c = min(max(y0 + 1, 0), 95);
        int x0c = min(max(x0i, 0), 95), x1c = min(max(x0i + 1, 0), 95);
        float mp = Pp[p];
        float w00 = ay0 * ax0 * mp, w01 = ay0 * ax1 * mp;
        float w10 = ay1 * ax0 * mp, w11 = ay1 * ax1 * mp;
        bf16x8 v00 = *(const bf16x8*)&xpn[(y0c * 96 + x0c) * 128];
        bf16x8 v01 = *(const bf16x8*)&xpn[(y0c * 96 + x1c) * 128];
        bf16x8 v10 = *(const bf16x8*)&xpn[(y1c * 96 + x0c) * 128];
        bf16x8 v11 = *(const bf16x8*)&xpn[(y1c * 96 + x1c) * 128];
#pragma unroll
        for (int e = 0; e < 8; ++e) {
          acc[e] += w00 * (float)v00[e] + w01 * (float)v01[e]
                  + w10 * (float)v10[e] + w11 * (float)v11[e];
        }
      }
    }
    bf16x8 o;
#pragma unroll
    for (int e = 0; e < 8; ++e) o[e] = (bf16)acc[e];
    *(bf16x8*)&Avs[pxl * LDA + g * 16 + c8] = o;
  }
  __syncthreads();

  // ---- fused output projection: Avs[32][128] @ Wop[128][128]^T + op_b, ReLU
  {
    int wv = t >> 6, lane = t & 63;
    int lrow = lane & 15, q = lane >> 4;
    int mrow0 = (wv & 1) * 16;          // which 16-px half
    int n0 = (wv >> 1) * 32;            // 4 col-groups of 32
    f32x4 pacc[2];
#pragma unroll
    for (int j = 0; j < 2; ++j)
#pragma unroll
      for (int e = 0; e < 4; ++e) pacc[j][e] = 0.f;
#pragma unroll
    for (int ks = 0; ks < 4; ++ks) {
      int ko = ks * 32 + q * 8;
      bf16x8 afr  = *(const bf16x8*)&Avs[(mrow0 + lrow) * LDA + ko];
      bf16x8 bfr0 = *(const bf16x8*)&Wop[(size_t)(n0 + lrow) * 128 + ko];
      bf16x8 bfr1 = *(const bf16x8*)&Wop[(size_t)(n0 + 16 + lrow) * 128 + ko];
      pacc[0] = __builtin_amdgcn_mfma_f32_16x16x32_bf16(afr, bfr0, pacc[0], 0, 0, 0);
      pacc[1] = __builtin_amdgcn_mfma_f32_16x16x32_bf16(afr, bfr1, pacc[1], 0, 0, 0);
    }
#pragma unroll
    for (int nj = 0; nj < 2; ++nj) {
      int col = n0 + nj * 16 + lrow;
      float bb = op_b[col];
#pragma unroll
      for (int r = 0; r < 4; ++r) {
        int px = mrow0 + q * 4 + r;
        Cs[col * 33 + px] = fmaxf(pacc[nj][r] + bb, 0.f);
      }
    }
  }
  __syncthreads();

  // ---- coalesced NCHW store: 8 lanes cover one channel's 128B (32 px)
  {
    int nn = (wg * 32) / NPIX;           // all 32 px share one image
    int hwb = wg * 32 - nn * NPIX;
    int img = nn & 3; int choff = (nn >= 4) ? 256 : 0;
    float* ob = out + (size_t)(img * 384 + choff) * NPIX + hwb;
#pragma unroll
    for (int i = t; i < 1024; i += 512) {
      int col = i >> 3, f4 = i & 7;
      f32x4 v = *(const f32x4*)&Cs[col * 33 + f4 * 4];
      *(f32x4*)&ob[(size_t)col * NPIX + f4 * 4] = v;
    }
  }
}

// ---------------------------------------------------------------------------
extern "C" void kernel_launch(void* const* d_in, const int* in_sizes, int n_in,
                              void* d_out, int out_size, void* d_ws, size_t ws_size,
                              hipStream_t stream)
{
  (void)in_sizes; (void)n_in; (void)out_size; (void)ws_size;
  const float* x0      = (const float*)d_in[0];
  const float* x1      = (const float*)d_in[1];
  const float* x2      = (const float*)d_in[2];
  const float* conv_w  = (const float*)d_in[3];
  const float* conv_g  = (const float*)d_in[4];
  const float* conv_b  = (const float*)d_in[5];
  const float* conv_rm = (const float*)d_in[6];
  const float* conv_rv = (const float*)d_in[7];
  const float* conv1_w = (const float*)d_in[8];
  const float* conv1_g = (const float*)d_in[9];
  const float* conv1_b = (const float*)d_in[10];
  const float* conv1_rm= (const float*)d_in[11];
  const float* conv1_rv= (const float*)d_in[12];
  const float* conv2_w = (const float*)d_in[13];
  const float* conv2_g = (const float*)d_in[14];
  const float* conv2_b = (const float*)d_in[15];
  const float* conv2_rm= (const float*)d_in[16];
  const float* conv2_rv= (const float*)d_in[17];
  const float* dw_w    = (const float*)d_in[18];
  const float* dw_b    = (const float*)d_in[19];
  const float* ln_g    = (const float*)d_in[20];
  const float* ln_b    = (const float*)d_in[21];
  const float* off_w   = (const float*)d_in[22];
  const float* off_b   = (const float*)d_in[23];
  const float* m_w     = (const float*)d_in[24];
  const float* m_b     = (const float*)d_in[25];
  const float* ip_w    = (const float*)d_in[26];
  const float* ip_b    = (const float*)d_in[27];
  const float* op_w    = (const float*)d_in[28];
  const float* op_b    = (const float*)d_in[29];
  float* out = (float*)d_out;
  char* WS = (char*)d_ws;

  // byte layout (R7-proven):
  // 0         featb   18.9 MB  (imgs 0-3 feat1b, imgs 4-7 feat2b)
  // 18874368  y2b     37.7 MB  (dead after conv2) ; xpb aliases (written
  //                            by mm_ip AFTER conv2 completed -> safe)
  // 56623104  y1b      2.36 MB
  // 58982400  offm    33.0 MB  (f16 73728x224)
  // 125042688 WTSf / WTSb
  bf16* featb  = (bf16*)WS;
  bf16* feat1b = featb;
  bf16* feat2b = featb + 4718592;
  bf16* y2b    = (bf16*)(WS + 18874368);
  bf16* xpb    = (bf16*)(WS + 18874368);         // alias, written after conv2
  bf16* y1b    = (bf16*)(WS + 56623104);
  f16*  offm   = (f16*)(WS + 58982400);
  float* WTSf  = (float*)(WS + 125042688);       // 608 floats
  bf16*  WTSb  = (bf16*)(WS + 125045120);        // 249856 bf16

  float* b1f  = WTSf;
  float* b1bf = WTSf + 128;
  float* b2f  = WTSf + 256;
  float* bomf = WTSf + 384;
  bf16* W1b  = WTSb;
  bf16* W1bb = WTSb + 32768;
  bf16* W2b  = WTSb + 40960;
  bf16* Wipb = WTSb + 188416;
  bf16* Womb = WTSb + 204800;
  bf16* Wopb = WTSb + 233472;

  prep_kernel<<<979, 256, 0, stream>>>(
      conv_w, conv_g, conv_b, conv_rm, conv_rv,
      conv1_w, conv1_g, conv1_b, conv1_rm, conv1_rv,
      conv2_w, conv2_g, conv2_b, conv2_rm, conv2_rv,
      ip_w, op_w, off_w, m_w, off_b, m_b, WTSf, WTSb);

  // both 1x1 convs in one launch (x2: 2304 blocks, x1: 144 blocks)
  c1x1_dual_kernel<<<2448, 256, 0, stream>>>(x1, W1b, b1f, x2, W1bb, b1bf, y1b, y2b);

  upsample_kernel<<<4608, 256, 0, stream>>>(y1b, feat1b);
  conv2_mfma_kernel<<<576, 256, 0, stream>>>(y2b, W2b, b2f, feat2b);

  // fused dual-branch DCNv3 (M = 73728)
  mm_ip_kernel<<<1152, 256, 0, stream>>>(featb, Wipb, ip_b, xpb);
  dwom_kernel<<<4608, 256, 0, stream>>>(featb, dw_w, dw_b, ln_g, ln_b, Womb, bomf, offm);

  // sample+op-proj (2304) || x0 copy (2304) in one launch
  sample_copy_kernel<<<4608, 512, 0, stream>>>(xpb, offm, Wopb, op_b,
                                               (const float4*)x0, out);
}

// Round 13
// 354.870 us; speedup vs baseline: 1.0646x; 1.0018x over previous
//
#include <hip/hip_runtime.h>
#include <cstdint>
#include <cstddef>

#define EPSV 1e-5f
#define NPIX 9216          // 96*96
#define LDA 136            // padded bf16 k-stride for 128-wide K chunks
#define LDK 72             // padded bf16 k-stride for 64-wide K chunks

typedef __bf16 bf16;
typedef _Float16 f16;
typedef __attribute__((ext_vector_type(8))) __bf16 bf16x8;
typedef __attribute__((ext_vector_type(4))) __bf16 bf16x4;
typedef __attribute__((ext_vector_type(2))) _Float16 f16x2;
typedef __attribute__((ext_vector_type(4))) float  f32x4;

__device__ __forceinline__ float silu_f(float v) { return v / (1.f + __expf(-v)); }

// ---------------------------------------------------------------------------
// WTSf (float, 608): b1[128] | b1b[128] | b2[128] | bom[224]
// WTSb (bf16, 249856), all [co][ci]:
//   0       W1b  [128][256]  (x1 1x1, BN-folded)
//   32768   W1bb [128][64]   (x2 1x1, BN-folded)
//   40960   W2b  [9][128][128] (3x3 s2, BN-folded, k-major)
//   188416  Wipb [128][128]
//   204800  Womb [224][128]  (rows 216..223 zero)
//   233472  Wopb [128][128]
// ---------------------------------------------------------------------------
__global__ __launch_bounds__(256) void prep_kernel(
    const float* __restrict__ conv_w, const float* __restrict__ conv_g,
    const float* __restrict__ conv_b, const float* __restrict__ conv_rm, const float* __restrict__ conv_rv,
    const float* __restrict__ conv1_w, const float* __restrict__ conv1_g,
    const float* __restrict__ conv1_b, const float* __restrict__ conv1_rm, const float* __restrict__ conv1_rv,
    const float* __restrict__ conv2_w, const float* __restrict__ conv2_g,
    const float* __restrict__ conv2_bb, const float* __restrict__ conv2_rm, const float* __restrict__ conv2_rv,
    const float* __restrict__ ip_w, const float* __restrict__ op_w,
    const float* __restrict__ off_w, const float* __restrict__ m_w,
    const float* __restrict__ off_b, const float* __restrict__ m_b,
    float* __restrict__ WTSf, bf16* __restrict__ WTSb)
{
  int idx = blockIdx.x * 256 + threadIdx.x;
  if (idx < 608) {
    if (idx < 128) {
      int co = idx;
      float s = conv_g[co] * rsqrtf(conv_rv[co] + EPSV);
      WTSf[idx] = conv_b[co] - conv_rm[co] * s;
    } else if (idx < 256) {
      int co = idx - 128;
      float s = conv1_g[co] * rsqrtf(conv1_rv[co] + EPSV);
      WTSf[idx] = conv1_b[co] - conv1_rm[co] * s;
    } else if (idx < 384) {
      int co = idx - 256;
      float s = conv2_g[co] * rsqrtf(conv2_rv[co] + EPSV);
      WTSf[idx] = conv2_bb[co] - conv2_rm[co] * s;
    } else {
      int col = idx - 384;
      WTSf[idx] = (col < 144) ? off_b[col] : (col < 216 ? m_b[col - 144] : 0.f);
    }
  } else {
    int j = idx - 608;
    if (j < 32768) {
      int co = j >> 8, ci = j & 255;
      float s = conv_g[co] * rsqrtf(conv_rv[co] + EPSV);
      WTSb[j] = (bf16)(conv_w[co * 256 + ci] * s);
    } else if (j < 40960) {
      int r = j - 32768; int co = r >> 6, ci = r & 63;
      float s = conv1_g[co] * rsqrtf(conv1_rv[co] + EPSV);
      WTSb[j] = (bf16)(conv1_w[co * 64 + ci] * s);
    } else if (j < 188416) {
      int r = j - 40960; int kp = r >> 14; int rr = r & 16383;
      int co = rr >> 7, ci = rr & 127;
      float s = conv2_g[co] * rsqrtf(conv2_rv[co] + EPSV);
      WTSb[j] = (bf16)(conv2_w[(co * 128 + ci) * 9 + kp] * s);
    } else if (j < 204800) {
      int r = j - 188416; int co = r >> 7, ci = r & 127;
      WTSb[j] = (bf16)ip_w[co * 128 + ci];
    } else if (j < 233472) {
      int r = j - 204800; int co = r >> 7, ci = r & 127;
      float v = (co < 144) ? off_w[co * 128 + ci] : (co < 216 ? m_w[(co - 144) * 128 + ci] : 0.f);
      WTSb[j] = (bf16)v;
    } else if (j < 249856) {
      int r = j - 233472; int co = r >> 7, ci = r & 127;
      WTSb[j] = (bf16)op_w[co * 128 + ci];
    }
  }
}

// ---------------------------------------------------------------------------
// 1x1 conv body via MFMA: NCHW fp32 (K ch) -> NHWC bf16 (128 ch) + BN + SiLU
// ---------------------------------------------------------------------------
__device__ __forceinline__ void c1x1_body(
    bf16* As, bf16* Bs, const float* __restrict__ x, const bf16* __restrict__ W,
    const float* __restrict__ bias, int K, int HW, int m0, bf16* __restrict__ outb)
{
  int t = threadIdx.x;
  int n = m0 / HW; int hw0 = m0 - n * HW;
  const float* xn = x + (size_t)n * K * HW;
  int wv = t >> 6, lane = t & 63;
  int lrow = lane & 15, q = lane >> 4;
  int n0 = wv * 32;
  f32x4 acc[4][2];
#pragma unroll
  for (int i = 0; i < 4; ++i)
#pragma unroll
    for (int j = 0; j < 2; ++j)
#pragma unroll
      for (int e = 0; e < 4; ++e) acc[i][j][e] = 0.f;

  for (int k0 = 0; k0 < K; k0 += 64) {
    if (k0) __syncthreads();
    for (int i = t; i < 1024; i += 256) {
      int px = i & 63; int ci4 = (i >> 6) << 2;
      bf16x4 p;
#pragma unroll
      for (int j = 0; j < 4; ++j)
        p[j] = (bf16)xn[(size_t)(k0 + ci4 + j) * HW + hw0 + px];
      *(bf16x4*)&As[px * LDK + ci4] = p;
    }
    for (int i = t; i < 1024; i += 256) {
      int co = i >> 3; int k8 = (i & 7) << 3;
      *(bf16x8*)&Bs[co * LDK + k8] = *(const bf16x8*)&W[(size_t)co * K + k0 + k8];
    }
    __syncthreads();
#pragma unroll
    for (int ks = 0; ks < 2; ++ks) {
      int ko = ks * 32 + q * 8;
      bf16x8 bfr0 = *(const bf16x8*)&Bs[(n0 + lrow) * LDK + ko];
      bf16x8 bfr1 = *(const bf16x8*)&Bs[(n0 + 16 + lrow) * LDK + ko];
#pragma unroll
      for (int mi = 0; mi < 4; ++mi) {
        bf16x8 afr = *(const bf16x8*)&As[(mi * 16 + lrow) * LDK + ko];
        acc[mi][0] = __builtin_amdgcn_mfma_f32_16x16x32_bf16(afr, bfr0, acc[mi][0], 0, 0, 0);
        acc[mi][1] = __builtin_amdgcn_mfma_f32_16x16x32_bf16(afr, bfr1, acc[mi][1], 0, 0, 0);
      }
    }
  }
#pragma unroll
  for (int mi = 0; mi < 4; ++mi) {
#pragma unroll
    for (int nj = 0; nj < 2; ++nj) {
      int co = n0 + nj * 16 + lrow;
      float bb = bias[co];
#pragma unroll
      for (int r = 0; r < 4; ++r) {
        int m = m0 + mi * 16 + q * 4 + r;
        outb[(size_t)m * 128 + co] = (bf16)silu_f(acc[mi][nj][r] + bb);
      }
    }
  }
}

// ---------------------------------------------------------------------------
// DUAL 1x1 conv launch: blocks [0,2304) = x2 path (K=64), [2304,2448) = x1
// path (K=256). Independent I/O; packs the 144-block x1 conv into the x2
// conv's shadow.
// ---------------------------------------------------------------------------
__global__ __launch_bounds__(256) void c1x1_dual_kernel(
    const float* __restrict__ x1, const bf16* __restrict__ W1b, const float* __restrict__ b1f,
    const float* __restrict__ x2, const bf16* __restrict__ W1bb, const float* __restrict__ b1bf,
    bf16* __restrict__ y1b, bf16* __restrict__ y2b)
{
  __shared__ bf16 As[64 * LDK];
  __shared__ bf16 Bs[128 * LDK];
  int bid = blockIdx.x;
  if (bid < 2304) {
    c1x1_body(As, Bs, x2, W1bb, b1bf, 64, 36864, bid << 6, y2b);
  } else {
    c1x1_body(As, Bs, x1, W1b, b1f, 256, 2304, (bid - 2304) << 6, y1b);
  }
}

// ---------------------------------------------------------------------------
// bilinear 2x upsample, NHWC bf16 -> bf16 ; thread = 4 channels
// ---------------------------------------------------------------------------
__global__ __launch_bounds__(256) void upsample_kernel(
    const bf16* __restrict__ y1b, bf16* __restrict__ feat1b)
{
  int idx = blockIdx.x * 256 + threadIdx.x;   // 1,179,648 total
  int c4 = (idx & 31) << 2;
  int pw = idx >> 5;
  int ow = pw % 96; int t1 = pw / 96;
  int oh = t1 % 96; int n = t1 / 96;
  float sh = oh * 0.5f - 0.25f, sw = ow * 0.5f - 0.25f;
  float hf = floorf(sh), wf = floorf(sw);
  float fy = sh - hf, fx = sw - wf;
  int h0 = (int)hf, w0 = (int)wf;
  int h0c = max(h0, 0), h1c = min(h0 + 1, 47);
  int w0c = max(w0, 0), w1c = min(w0 + 1, 47);
  const bf16* yn = y1b + (size_t)n * 2304 * 128 + c4;
  bf16x4 v00 = *(const bf16x4*)&yn[(h0c * 48 + w0c) * 128];
  bf16x4 v01 = *(const bf16x4*)&yn[(h0c * 48 + w1c) * 128];
  bf16x4 v10 = *(const bf16x4*)&yn[(h1c * 48 + w0c) * 128];
  bf16x4 v11 = *(const bf16x4*)&yn[(h1c * 48 + w1c) * 128];
  bf16x4 o;
#pragma unroll
  for (int e = 0; e < 4; ++e) {
    float v = (1.f - fy) * ((1.f - fx) * (float)v00[e] + fx * (float)v01[e])
            + fy * ((1.f - fx) * (float)v10[e] + fx * (float)v11[e]);
    o[e] = (bf16)v;
  }
  *(bf16x4*)&feat1b[((size_t)n * NPIX + oh * 96 + ow) * 128 + c4] = o;
}

// ---------------------------------------------------------------------------
// conv2 via MFMA: 3x3 s2 p1 + BN + SiLU. y2b NHWC bf16 -> feat2b.
// ---------------------------------------------------------------------------
__global__ __launch_bounds__(256) void conv2_mfma_kernel(
    const bf16* __restrict__ y2b, const bf16* __restrict__ W2b,
    const float* __restrict__ b2, bf16* __restrict__ feat2b)
{
  __shared__ bf16 As[64 * LDA];
  __shared__ bf16 Bs[128 * LDA];
  int m0 = blockIdx.x << 6;
  int t = threadIdx.x;
  int wv = t >> 6, lane = t & 63;
  int lrow = lane & 15, q = lane >> 4;
  int n0 = wv * 32;
  f32x4 acc[4][2];
#pragma unroll
  for (int i = 0; i < 4; ++i)
#pragma unroll
    for (int j = 0; j < 2; ++j)
#pragma unroll
      for (int e = 0; e < 4; ++e) acc[i][j][e] = 0.f;
  bf16x8 zv;
#pragma unroll
  for (int e = 0; e < 8; ++e) zv[e] = (bf16)0.f;

  for (int kp = 0; kp < 9; ++kp) {
    int kh = kp / 3, kw = kp - kh * 3;
    __syncthreads();
    for (int i = t; i < 1024; i += 256) {
      int row = i >> 4; int c8 = (i & 15) << 3;
      int m = m0 + row;
      int nimg = m / NPIX; int hw = m - nimg * NPIX;
      int oh = hw / 96, ow = hw - oh * 96;
      int ih = 2 * oh - 1 + kh, iw = 2 * ow - 1 + kw;
      bf16x8 v = zv;
      if ((unsigned)ih < 192u && (unsigned)iw < 192u)
        v = *(const bf16x8*)&y2b[(((size_t)nimg * 192 + ih) * 192 + iw) * 128 + c8];
      *(bf16x8*)&As[row * LDA + c8] = v;
    }
    const bf16* Wk = W2b + kp * 16384;
    for (int i = t; i < 2048; i += 256) {
      int nn = i >> 4; int k8 = (i & 15) << 3;
      *(bf16x8*)&Bs[nn * LDA + k8] = *(const bf16x8*)&Wk[nn * 128 + k8];
    }
    __syncthreads();
#pragma unroll
    for (int ks = 0; ks < 4; ++ks) {
      bf16x8 bfr0 = *(const bf16x8*)&Bs[(n0 + lrow) * LDA + ks * 32 + q * 8];
      bf16x8 bfr1 = *(const bf16x8*)&Bs[(n0 + 16 + lrow) * LDA + ks * 32 + q * 8];
#pragma unroll
      for (int mi = 0; mi < 4; ++mi) {
        bf16x8 afr = *(const bf16x8*)&As[(mi * 16 + lrow) * LDA + ks * 32 + q * 8];
        acc[mi][0] = __builtin_amdgcn_mfma_f32_16x16x32_bf16(afr, bfr0, acc[mi][0], 0, 0, 0);
        acc[mi][1] = __builtin_amdgcn_mfma_f32_16x16x32_bf16(afr, bfr1, acc[mi][1], 0, 0, 0);
      }
    }
  }
#pragma unroll
  for (int mi = 0; mi < 4; ++mi) {
#pragma unroll
    for (int nj = 0; nj < 2; ++nj) {
      int co = n0 + nj * 16 + lrow;
      float bb = b2[co];
#pragma unroll
      for (int r = 0; r < 4; ++r) {
        int m = m0 + mi * 16 + q * 4 + r;
        feat2b[(size_t)m * 128 + co] = (bf16)silu_f(acc[mi][nj][r] + bb);
      }
    }
  }
}

// ---------------------------------------------------------------------------
// MERGED dwom + ip launch (both read featb, independent outputs):
// blocks [0,4608)    = dwom body: dw3x3+LN+GELU -> om-GEMM -> f16 offm
// blocks [4608,9216) = ip body: featb 16px tile @ Wipb -> bf16 xpb
// LDS union: dwom 10496 B vs ip 8704 B -> 10496 B (no occupancy tax).
// ---------------------------------------------------------------------------
__global__ __launch_bounds__(256) void dwom_ip_kernel(
    const bf16* __restrict__ featb, const float* __restrict__ dw_w,
    const float* __restrict__ dw_b, const float* __restrict__ ln_g,
    const float* __restrict__ ln_b, const bf16* __restrict__ Wom,
    const float* __restrict__ bom, const bf16* __restrict__ Wip,
    const float* __restrict__ ip_b, f16* __restrict__ offm,
    bf16* __restrict__ xpb)
{
  __shared__ char LB[10496];
  int t = threadIdx.x;
  int bid = blockIdx.x;

  if (bid >= 4608) {
    // ================= ip body: 16-px tile GEMM vs Wipb ==================
    bf16* Ds = (bf16*)LB;                 // [16][LDA] = 4352 B
    bf16* Xs = (bf16*)(LB + 4352);        // [16][LDA] = 4352 B
    int pixel0 = (bid - 4608) * 16;
    {
      int pxl = t >> 4;
      int c8 = (t & 15) << 3;
      *(bf16x8*)&Ds[pxl * LDA + c8] =
          *(const bf16x8*)&featb[(size_t)(pixel0 + pxl) * 128 + c8];
    }
    __syncthreads();
    {
      int wv = t >> 6, lane = t & 63;
      int lrow = lane & 15, q = lane >> 4;
      int n0 = wv * 32;
      f32x4 pacc[2];
#pragma unroll
      for (int j = 0; j < 2; ++j)
#pragma unroll
        for (int e = 0; e < 4; ++e) pacc[j][e] = 0.f;
#pragma unroll
      for (int ks = 0; ks < 4; ++ks) {
        int ko = ks * 32 + q * 8;
        bf16x8 afr  = *(const bf16x8*)&Ds[lrow * LDA + ko];
        bf16x8 bfr0 = *(const bf16x8*)&Wip[(size_t)(n0 + lrow) * 128 + ko];
        bf16x8 bfr1 = *(const bf16x8*)&Wip[(size_t)(n0 + 16 + lrow) * 128 + ko];
        pacc[0] = __builtin_amdgcn_mfma_f32_16x16x32_bf16(afr, bfr0, pacc[0], 0, 0, 0);
        pacc[1] = __builtin_amdgcn_mfma_f32_16x16x32_bf16(afr, bfr1, pacc[1], 0, 0, 0);
      }
#pragma unroll
      for (int nj = 0; nj < 2; ++nj) {
        int col = n0 + nj * 16 + lrow;
        float bb = ip_b[col];
#pragma unroll
        for (int r = 0; r < 4; ++r)
          Xs[(q * 4 + r) * LDA + col] = (bf16)(pacc[nj][r] + bb);
      }
    }
    __syncthreads();
    {
      int pxl = t >> 4;
      int c8 = (t & 15) << 3;
      *(bf16x8*)&xpb[(size_t)(pixel0 + pxl) * 128 + c8] =
          *(const bf16x8*)&Xs[pxl * LDA + c8];
    }
    return;
  }

  // ================= dwom body =================
  float* Wts = (float*)LB;              // 4608 B  (dw_w [9][128])
  float* Pb  = (float*)(LB + 4608);     // 1536 B  (dw_b | ln_g | ln_b)
  bf16*  Ds  = (bf16*)(LB + 6144);      // 4352 B  ([16px][128ch] tile)
  for (int i = t; i < 1152; i += 256) Wts[i] = dw_w[i];
  for (int i = t; i < 384; i += 256)
    Pb[i] = (i < 128) ? dw_b[i] : (i < 256 ? ln_g[i - 128] : ln_b[i - 256]);
  __syncthreads();

  int wg = (bid & 7) * 576 + (bid >> 3);   // XCD swizzle (4608 = 8*576)
  {
    int pxl = t >> 4;
    int c8 = (t & 15) << 3;
    int pixel = wg * 16 + pxl;
    int n = pixel / NPIX; int hw = pixel - n * NPIX;
    int h = hw / 96; int w = hw - h * 96;
    const bf16* fn = featb + (size_t)n * NPIX * 128 + c8;
    bf16x8 zv;
#pragma unroll
    for (int e = 0; e < 8; ++e) zv[e] = (bf16)0.f;

    bf16x8 v[9];
#pragma unroll
    for (int p = 0; p < 9; ++p) {
      int hh = h + p / 3 - 1, ww = w + (p % 3) - 1;
      bool valid = ((unsigned)hh < 96u) && ((unsigned)ww < 96u);
      int hc = min(max(hh, 0), 95), wc = min(max(ww, 0), 95);
      bf16x8 x = *(const bf16x8*)&fn[(hc * 96 + wc) * 128];
      v[p] = valid ? x : zv;
    }

    float acc[8];
#pragma unroll
    for (int e = 0; e < 8; ++e) acc[e] = Pb[c8 + e];
#pragma unroll
    for (int p = 0; p < 9; ++p) {
      f32x4 w0 = *(const f32x4*)&Wts[p * 128 + c8];
      f32x4 w1 = *(const f32x4*)&Wts[p * 128 + c8 + 4];
#pragma unroll
      for (int e = 0; e < 4; ++e) {
        acc[e]     += (float)v[p][e]     * w0[e];
        acc[4 + e] += (float)v[p][4 + e] * w1[e];
      }
    }

    float s = 0.f, qs = 0.f;
#pragma unroll
    for (int e = 0; e < 8; ++e) { s += acc[e]; qs += acc[e] * acc[e]; }
#pragma unroll
    for (int off = 8; off > 0; off >>= 1) {
      s  += __shfl_xor(s, off);
      qs += __shfl_xor(qs, off);
    }
    float mean = s * (1.f / 128.f);
    float var = qs * (1.f / 128.f) - mean * mean;
    float rstd = rsqrtf(var + EPSV);
    bf16x8 o;
#pragma unroll
    for (int e = 0; e < 8; ++e) {
      float xn = (acc[e] - mean) * rstd * Pb[128 + c8 + e] + Pb[256 + c8 + e];
      float z = 0.7978845608028654f * (xn + 0.044715f * xn * xn * xn);
      float th;
      if (z > 15.f) th = 1.f;
      else if (z < -15.f) th = -1.f;
      else { float e2 = __expf(2.f * z); th = (e2 - 1.f) / (e2 + 1.f); }
      o[e] = (bf16)(0.5f * xn * (1.f + th));
    }
    *(bf16x8*)&Ds[pxl * LDA + c8] = o;
  }
  __syncthreads();

  // offset/mask GEMM: Ds[16][128] @ Wom[224][128]^T + bom -> f16 offm
  {
    int wv = t >> 6, lane = t & 63;
    int lrow = lane & 15, q = lane >> 4;
    f16* orow = offm + (size_t)(wg * 16) * 224;
    for (int gsel = wv; gsel < 7; gsel += 4) {
      int n0 = gsel * 32;
      f32x4 pacc[2];
#pragma unroll
      for (int j = 0; j < 2; ++j)
#pragma unroll
        for (int e = 0; e < 4; ++e) pacc[j][e] = 0.f;
#pragma unroll
      for (int ks = 0; ks < 4; ++ks) {
        int ko = ks * 32 + q * 8;
        bf16x8 afr  = *(const bf16x8*)&Ds[lrow * LDA + ko];
        bf16x8 bfr0 = *(const bf16x8*)&Wom[(size_t)(n0 + lrow) * 128 + ko];
        bf16x8 bfr1 = *(const bf16x8*)&Wom[(size_t)(n0 + 16 + lrow) * 128 + ko];
        pacc[0] = __builtin_amdgcn_mfma_f32_16x16x32_bf16(afr, bfr0, pacc[0], 0, 0, 0);
        pacc[1] = __builtin_amdgcn_mfma_f32_16x16x32_bf16(afr, bfr1, pacc[1], 0, 0, 0);
      }
#pragma unroll
      for (int nj = 0; nj < 2; ++nj) {
        int col = n0 + nj * 16 + lrow;
        float bb = bom[col];
#pragma unroll
        for (int r = 0; r < 4; ++r) {
          int px = q * 4 + r;
          orow[(size_t)px * 224 + col] = (f16)(pacc[nj][r] + bb);
        }
      }
    }
  }
}

// ---------------------------------------------------------------------------
// Deformable sampling + output projection, PLUS independent x0 copy riding
// in blocks [2304,4608): sample is latency-bound at ~17% HBM, the pure-copy
// blocks stream x0 during its stalls.
// ---------------------------------------------------------------------------
__global__ __launch_bounds__(512, 6) void sample_copy_kernel(
    const bf16* __restrict__ xpb, const f16* __restrict__ offm,
    const bf16* __restrict__ Wop, const float* __restrict__ op_b,
    const float4* __restrict__ x0, float* __restrict__ out)
{
  __shared__ char LB[32256];
  int t = threadIdx.x;
  int bid = blockIdx.x;
  if (bid >= 2304) {
    // ---- x0 copy: 2304 blocks x 512 threads x 1 float4 = 1,179,648
    int idx = (bid - 2304) * 512 + t;
    int n = idx / (128 * 2304);
    int r = idx - n * (128 * 2304);
    float4* outv = (float4*)out;
    outv[(size_t)(n * 384 + 128) * 2304 + r] = x0[(size_t)n * 128 * 2304 + r];
    return;
  }
  uint32_t* Sd = (uint32_t*)LB;                 // 32 px * 224 f16 = 14336 B
  float*    Pm = (float*)(LB + 14336);          // 32 px * 72 f32  =  9216 B
  bf16*     Avs = (bf16*)(LB + 23552);          // [32][LDA] bf16  =  8704 B
  float*    Cs = (float*)LB;                    // [128][33] f32   = 16896 B (aliases Sd/Pm)
  const f16* S = (const f16*)Sd;
  int wg = (bid & 7) * 288 + (bid >> 3);   // XCD-chunked swizzle (2304 = 8*288)
  {
    const uint32_t* src = (const uint32_t*)(offm + (size_t)wg * 32 * 224);
    for (int i = t; i < 3584; i += 512) Sd[i] = src[i];
  }
  __syncthreads();
  if (t < 256) {
    int px = t >> 3, gg = t & 7;
    const f16* L = S + px * 224 + 144 + gg * 9;
    float l[9]; float mx = -1e30f;
#pragma unroll
    for (int p = 0; p < 9; ++p) { l[p] = (float)L[p]; mx = fmaxf(mx, l[p]); }
    float se = 0.f;
#pragma unroll
    for (int p = 0; p < 9; ++p) { l[p] = __expf(l[p] - mx); se += l[p]; }
    float inv = 1.f / se;
    float* Pp = Pm + px * 72 + gg * 9;
#pragma unroll
    for (int p = 0; p < 9; ++p) Pp[p] = l[p] * inv;
  }
  __syncthreads();
  {
    int pxl = t >> 4;                       // 0..31
    int tid16 = t & 15;
    int g = tid16 >> 1;
    int c8 = (tid16 & 1) << 3;
    int pixel = wg * 32 + pxl;
    int n = pixel / NPIX; int hw = pixel - n * NPIX;
    int h = hw / 96; int w = hw - h * 96;
    const f16* Sp = S + pxl * 224 + g * 18;
    const float* Pp = Pm + pxl * 72 + g * 9;
    const bf16* xpn = xpb + (size_t)n * NPIX * 128 + g * 16 + c8;
    float acc[8];
#pragma unroll
    for (int e = 0; e < 8; ++e) acc[e] = 0.f;
#pragma unroll 1
    for (int kh = 0; kh < 3; ++kh) {
#pragma unroll
      for (int kw = 0; kw < 3; ++kw) {
        int p = kh * 3 + kw;
        f16x2 d2 = *(const f16x2*)&Sp[p * 2];   // 4B-aligned (even index)
        float dx = (float)d2.x, dy = (float)d2.y;
        float pyu = (float)(h + kh - 1) + dy;
        float pxu = (float)(w + kw - 1) + dx;
        float yf = floorf(pyu), xf = floorf(pxu);
        float wy = pyu - yf, wx = pxu - xf;
        int y0 = (int)yf, x0i = (int)xf;
        float ay0 = ((unsigned)y0 < 96u) ? (1.f - wy) : 0.f;
        float ay1 = ((unsigned)(y0 + 1) < 96u) ? wy : 0.f;
        float ax0 = ((unsigned)x0i < 96u) ? (1.f - wx) : 0.f;
        float ax1 = ((unsigned)(x0i + 1) < 96u) ? wx : 0.f;
        int y0c = min(max(y0, 0), 95), y1c = min(max(y0 + 1, 0), 95);
        int x0c = min(max(x0i, 0), 95), x1c = min(max(x0i + 1, 0), 95);
        float mp = Pp[p];
        float w00 = ay0 * ax0 * mp, w01 = ay0 * ax1 * mp;
        float w10 = ay1 * ax0 * mp, w11 = ay1 * ax1 * mp;
        bf16x8 v00 = *(const bf16x8*)&xpn[(y0c * 96 + x0c) * 128];
        bf16x8 v01 = *(const bf16x8*)&xpn[(y0c * 96 + x1c) * 128];
        bf16x8 v10 = *(const bf16x8*)&xpn[(y1c * 96 + x0c) * 128];
        bf16x8 v11 = *(const bf16x8*)&xpn[(y1c * 96 + x1c) * 128];
#pragma unroll
        for (int e = 0; e < 8; ++e) {
          acc[e] += w00 * (float)v00[e] + w01 * (float)v01[e]
                  + w10 * (float)v10[e] + w11 * (float)v11[e];
        }
      }
    }
    bf16x8 o;
#pragma unroll
    for (int e = 0; e < 8; ++e) o[e] = (bf16)acc[e];
    *(bf16x8*)&Avs[pxl * LDA + g * 16 + c8] = o;
  }
  __syncthreads();

  // ---- fused output projection: Avs[32][128] @ Wop[128][128]^T + op_b, ReLU
  {
    int wv = t >> 6, lane = t & 63;
    int lrow = lane & 15, q = lane >> 4;
    int mrow0 = (wv & 1) * 16;          // which 16-px half
    int n0 = (wv >> 1) * 32;            // 4 col-groups of 32
    f32x4 pacc[2];
#pragma unroll
    for (int j = 0; j < 2; ++j)
#pragma unroll
      for (int e = 0; e < 4; ++e) pacc[j][e] = 0.f;
#pragma unroll
    for (int ks = 0; ks < 4; ++ks) {
      int ko = ks * 32 + q * 8;
      bf16x8 afr  = *(const bf16x8*)&Avs[(mrow0 + lrow) * LDA + ko];
      bf16x8 bfr0 = *(const bf16x8*)&Wop[(size_t)(n0 + lrow) * 128 + ko];
      bf16x8 bfr1 = *(const bf16x8*)&Wop[(size_t)(n0 + 16 + lrow) * 128 + ko];
      pacc[0] = __builtin_amdgcn_mfma_f32_16x16x32_bf16(afr, bfr0, pacc[0], 0, 0, 0);
      pacc[1] = __builtin_amdgcn_mfma_f32_16x16x32_bf16(afr, bfr1, pacc[1], 0, 0, 0);
    }
#pragma unroll
    for (int nj = 0; nj < 2; ++nj) {
      int col = n0 + nj * 16 + lrow;
      float bb = op_b[col];
#pragma unroll
      for (int r = 0; r < 4; ++r) {
        int px = mrow0 + q * 4 + r;
        Cs[col * 33 + px] = fmaxf(pacc[nj][r] + bb, 0.f);
      }
    }
  }
  __syncthreads();

  // ---- coalesced NCHW store: 8 lanes cover one channel's 128B (32 px)
  {
    int nn = (wg * 32) / NPIX;           // all 32 px share one image
    int hwb = wg * 32 - nn * NPIX;
    int img = nn & 3; int choff = (nn >= 4) ? 256 : 0;
    float* ob = out + (size_t)(img * 384 + choff) * NPIX + hwb;
#pragma unroll
    for (int i = t; i < 1024; i += 512) {
      int col = i >> 3, f4 = i & 7;
      f32x4 v = *(const f32x4*)&Cs[col * 33 + f4 * 4];
      *(f32x4*)&ob[(size_t)col * NPIX + f4 * 4] = v;
    }
  }
}

// ---------------------------------------------------------------------------
extern "C" void kernel_launch(void* const* d_in, const int* in_sizes, int n_in,
                              void* d_out, int out_size, void* d_ws, size_t ws_size,
                              hipStream_t stream)
{
  (void)in_sizes; (void)n_in; (void)out_size; (void)ws_size;
  const float* x0      = (const float*)d_in[0];
  const float* x1      = (const float*)d_in[1];
  const float* x2      = (const float*)d_in[2];
  const float* conv_w  = (const float*)d_in[3];
  const float* conv_g  = (const float*)d_in[4];
  const float* conv_b  = (const float*)d_in[5];
  const float* conv_rm = (const float*)d_in[6];
  const float* conv_rv = (const float*)d_in[7];
  const float* conv1_w = (const float*)d_in[8];
  const float* conv1_g = (const float*)d_in[9];
  const float* conv1_b = (const float*)d_in[10];
  const float* conv1_rm= (const float*)d_in[11];
  const float* conv1_rv= (const float*)d_in[12];
  const float* conv2_w = (const float*)d_in[13];
  const float* conv2_g = (const float*)d_in[14];
  const float* conv2_b = (const float*)d_in[15];
  const float* conv2_rm= (const float*)d_in[16];
  const float* conv2_rv= (const float*)d_in[17];
  const float* dw_w    = (const float*)d_in[18];
  const float* dw_b    = (const float*)d_in[19];
  const float* ln_g    = (const float*)d_in[20];
  const float* ln_b    = (const float*)d_in[21];
  const float* off_w   = (const float*)d_in[22];
  const float* off_b   = (const float*)d_in[23];
  const float* m_w     = (const float*)d_in[24];
  const float* m_b     = (const float*)d_in[25];
  const float* ip_w    = (const float*)d_in[26];
  const float* ip_b    = (const float*)d_in[27];
  const float* op_w    = (const float*)d_in[28];
  const float* op_b    = (const float*)d_in[29];
  float* out = (float*)d_out;
  char* WS = (char*)d_ws;

  // byte layout (R7-proven):
  // 0         featb   18.9 MB  (imgs 0-3 feat1b, imgs 4-7 feat2b)
  // 18874368  y2b     37.7 MB  (dead after conv2) ; xpb aliases (written
  //                            by dwom_ip AFTER conv2 completed -> safe)
  // 56623104  y1b      2.36 MB
  // 58982400  offm    33.0 MB  (f16 73728x224)
  // 125042688 WTSf / WTSb
  bf16* featb  = (bf16*)WS;
  bf16* feat1b = featb;
  bf16* feat2b = featb + 4718592;
  bf16* y2b    = (bf16*)(WS + 18874368);
  bf16* xpb    = (bf16*)(WS + 18874368);         // alias, written after conv2
  bf16* y1b    = (bf16*)(WS + 56623104);
  f16*  offm   = (f16*)(WS + 58982400);
  float* WTSf  = (float*)(WS + 125042688);       // 608 floats
  bf16*  WTSb  = (bf16*)(WS + 125045120);        // 249856 bf16

  float* b1f  = WTSf;
  float* b1bf = WTSf + 128;
  float* b2f  = WTSf + 256;
  float* bomf = WTSf + 384;
  bf16* W1b  = WTSb;
  bf16* W1bb = WTSb + 32768;
  bf16* W2b  = WTSb + 40960;
  bf16* Wipb = WTSb + 188416;
  bf16* Womb = WTSb + 204800;
  bf16* Wopb = WTSb + 233472;

  prep_kernel<<<979, 256, 0, stream>>>(
      conv_w, conv_g, conv_b, conv_rm, conv_rv,
      conv1_w, conv1_g, conv1_b, conv1_rm, conv1_rv,
      conv2_w, conv2_g, conv2_b, conv2_rm, conv2_rv,
      ip_w, op_w, off_w, m_w, off_b, m_b, WTSf, WTSb);

  // both 1x1 convs in one launch (x2: 2304 blocks, x1: 144 blocks)
  c1x1_dual_kernel<<<2448, 256, 0, stream>>>(x1, W1b, b1f, x2, W1bb, b1bf, y1b, y2b);

  upsample_kernel<<<4608, 256, 0, stream>>>(y1b, feat1b);
  conv2_mfma_kernel<<<576, 256, 0, stream>>>(y2b, W2b, b2f, feat2b);

  // dwom (4608) || ip-GEMM (4608) in one launch — both read featb
  dwom_ip_kernel<<<9216, 256, 0, stream>>>(featb, dw_w, dw_b, ln_g, ln_b,
                                           Womb, bomf, Wipb, ip_b, offm, xpb);

  // sample+op-proj (2304) || x0 copy (2304) in one launch
  sample_copy_kernel<<<4608, 512, 0, stream>>>(xpb, offm, Wopb, op_b,
                                               (const float4*)x0, out);
}